// Round 5
// baseline (1232.830 us; speedup 1.0000x reference)
//
#include <hip/hip_runtime.h>
#include <stdint.h>

// ---------------------------------------------------------------------------
// Qwen3.5-style layer on MI355X. fp32 in/out. Pre-router chain computed in
// split-bf16 (hi/lo) 3-pass MFMA => ~fp32 precision so the discrete top-2
// expert selection matches the fp32 reference. MoE GEMMs single bf16.
// R5: all GEMMs on m97 structure (128x128, global_load_lds w16, XCD swizzle).
// R6: attention K/V staged in LDS, XOR-swizzled, 2-barrier loop.
// R7/R8: GEMM LDS superrow-XOR swizzle (bank conflicts -> 0); delta ctx via
//     MFMA; vdT aliases dmh/dml (ws budget).
// R9: breadth: (a) MoE GEMMs 128x256 tiles (2x MFMA per barrier);
//     (b) both output projections merged into one 512-block launch;
//     (c) 3 vT transposes fused into one launch; (d) ksum fused into
//     delta_ctx2 (drop k_ksum kernel + a 16.8MB re-read).
// ---------------------------------------------------------------------------

typedef __attribute__((ext_vector_type(8))) short short8;   // 8 bf16 = 16B
typedef __attribute__((ext_vector_type(4))) float floatx4;

#define DMODEL 1024
#define SEQ    1024
#define NHEAD  16
#define DK     64
#define DFF    2048
#define NEXP   8
#define MAXTILE 144

__device__ __forceinline__ float bf2f(unsigned short h){
  union{unsigned u;float f;}v; v.u=((unsigned)h)<<16; return v.f;
}
__device__ __forceinline__ unsigned short f2bf(float f){
  union{float f;unsigned u;}v; v.f=f;
  unsigned r=(v.u + 0x7FFFu + ((v.u>>16)&1u))>>16; return (unsigned short)r;
}
__device__ __forceinline__ void splitbf(float v, unsigned short& hi, unsigned short& lo){
  hi = f2bf(v); lo = f2bf(v - bf2f(hi));
}

// async global->LDS, 16B per lane. LDS dest is wave-uniform base + lane*16.
__device__ __forceinline__ void glds16(const unsigned short* g, unsigned short* l){
  __builtin_amdgcn_global_load_lds(
      (const __attribute__((address_space(1))) void*)g,
      (__attribute__((address_space(3))) void*)l, 16, 0, 0);
}

__device__ __forceinline__ float block_sum(float v, float* red){
  for(int off=32;off;off>>=1) v += __shfl_down(v,off,64);
  int w = threadIdx.x>>6;
  __syncthreads();
  if((threadIdx.x&63)==0) red[w]=v;
  __syncthreads();
  return red[0]+red[1]+red[2]+red[3];
}

// ---- pack mask to bits: one wave per 64-int chunk --------------------------
__global__ __launch_bounds__(256) void k_maskpack(
    const int* __restrict__ mask, unsigned long long* __restrict__ mp){
  int gw = blockIdx.x*4 + (threadIdx.x>>6);
  int lane = threadIdx.x&63;
  unsigned long long bm = __ballot(mask[(long)gw*64 + lane] != 0);
  if(lane==0) mp[gw]=bm;
}

// ---- transpose fp32 -> split bf16 planes: dst[c][r] = src[r][c] ------------
__global__ __launch_bounds__(256) void k_transpose_f2(
    const float* __restrict__ src, unsigned short* __restrict__ dh,
    unsigned short* __restrict__ dl, long srs, long drs, long sbs, long dbs){
  __shared__ float t[32][33];
  src += (long)blockIdx.z*sbs; dh += (long)blockIdx.z*dbs; dl += (long)blockIdx.z*dbs;
  int c0 = blockIdx.x*32, r0 = blockIdx.y*32;
  int tx = threadIdx.x & 31, ty = threadIdx.x >> 5;
  for(int i=0;i<32;i+=8)
    t[ty+i][tx] = src[(long)(r0+ty+i)*srs + (c0+tx)];
  __syncthreads();
  for(int i=0;i<32;i+=8){
    unsigned short hi,lo; splitbf(t[tx][ty+i],hi,lo);
    long idx = (long)(c0+ty+i)*drs + (r0+tx);
    dh[idx]=hi; dl[idx]=lo;
  }
}

// ---- transpose fp32 -> single bf16 (MoE weights) ---------------------------
__global__ __launch_bounds__(256) void k_transpose_f(
    const float* __restrict__ src, unsigned short* __restrict__ dst,
    long srs, long drs, long sbs, long dbs){
  __shared__ float t[32][33];
  src += (long)blockIdx.z*sbs; dst += (long)blockIdx.z*dbs;
  int c0 = blockIdx.x*32, r0 = blockIdx.y*32;
  int tx = threadIdx.x & 31, ty = threadIdx.x >> 5;
  for(int i=0;i<32;i+=8)
    t[ty+i][tx] = src[(long)(r0+ty+i)*srs + (c0+tx)];
  __syncthreads();
  for(int i=0;i<32;i+=8)
    dst[(long)(c0+ty+i)*drs + (r0+tx)] = f2bf(t[tx][ty+i]);
}

// ---- vT3: 3 slices (v, kd, vd), both planes, all (b,h) in one launch -------
// blockIdx.y in [0,6): slice = y>>1, d0 = (y&1)*32. dst[bh][dk][s].
__global__ __launch_bounds__(256) void k_vt3(
    const unsigned short* __restrict__ qh, const unsigned short* __restrict__ ql,
    unsigned short* __restrict__ vTh, unsigned short* __restrict__ vTl,
    unsigned short* __restrict__ kdTh, unsigned short* __restrict__ kdTl,
    unsigned short* __restrict__ vdTh, unsigned short* __restrict__ vdTl){
  __shared__ unsigned short th[32][33], tl[32][33];
  int z = blockIdx.z, b = z>>4, h = z&15;
  int slice = blockIdx.y >> 1;
  long coff = (slice==0) ? 2048 : (slice==1 ? 4096 : 5120);
  unsigned short* dh = (slice==0) ? vTh : (slice==1 ? kdTh : vdTh);
  unsigned short* dl = (slice==0) ? vTl : (slice==1 ? kdTl : vdTl);
  int s0 = blockIdx.x*32, d0 = (blockIdx.y&1)*32;
  int tx = threadIdx.x & 31, ty = threadIdx.x >> 5;
  for(int i=0;i<32;i+=8){
    long src = (long)(b*SEQ + s0+ty+i)*6144 + coff + h*DK + d0+tx;
    th[ty+i][tx] = qh[src]; tl[ty+i][tx] = ql[src];
  }
  __syncthreads();
  for(int i=0;i<32;i+=8){
    long dst = ((long)z*DK + d0+ty+i)*SEQ + s0+tx;
    dh[dst] = th[tx][ty+i]; dl[dst] = tl[tx][ty+i];
  }
}

// ---- LayerNorm 1: fp32 x -> split bf16 h1 ----------------------------------
__global__ __launch_bounds__(256) void k_ln1(
    const float* __restrict__ x, const float* __restrict__ g,
    const float* __restrict__ b, unsigned short* __restrict__ oh,
    unsigned short* __restrict__ ol){
  __shared__ float red[4];
  int t = blockIdx.x, tid = threadIdx.x;
  long base = (long)t*DMODEL + tid*4;
  floatx4 xv = *(const floatx4*)(x + base);
  float v[4] = {xv[0], xv[1], xv[2], xv[3]};
  float s = block_sum(v[0]+v[1]+v[2]+v[3], red);
  float mu = s * (1.f/DMODEL);
  float q=0.f;
  for(int i=0;i<4;i++){ float d=v[i]-mu; q+=d*d; }
  q = block_sum(q, red);
  float inv = rsqrtf(q*(1.f/DMODEL) + 1e-5f);
  for(int i=0;i<4;i++){
    int d = tid*4+i;
    unsigned short hi,lo; splitbf((v[i]-mu)*inv*g[d] + b[d], hi, lo);
    oh[base+i]=hi; ol[base+i]=lo;
  }
}

// ---- split GEMM, m97 structure + superrow XOR swizzle ----------------------
// LDS tile [128 rows][32 shorts] viewed as [64 superrows][8 chunks of 16B].
// Logical (row, c4) stored at physical chunk p = ((row&1)*4|c4) ^ ((row>>1)&7).
// Staging keeps LINEAR glds dest (lane*16B) and permutes the GLOBAL source;
// reads apply the same XOR => 2 lanes/bank-quad (free) instead of 8-way.
template<int SPLIT>
__global__ __launch_bounds__(256) void k_gemm128_ss(
    const unsigned short* __restrict__ Ah, const unsigned short* __restrict__ Al,
    const unsigned short* __restrict__ Bh, const unsigned short* __restrict__ Bl,
    unsigned short* __restrict__ Ch, unsigned short* __restrict__ Cl,
    float* __restrict__ Cf, int K, int lda, int ldb, int ldc, int gridN){
  __shared__ unsigned short Ash[128*32], Asl[128*32];
  __shared__ unsigned short Bsh[128*32], Bsl[128*32];
  int nwg = gridDim.x, bid = blockIdx.x;
  int swz = (bid & 7)*(nwg >> 3) + (bid >> 3);       // XCD-contiguous chunks
  int bx = swz % gridN, by = swz / gridN;
  int m0 = by*128, n0 = bx*128;
  int tid = threadIdx.x, w = tid>>6, lane = tid&63;
  int qm = lane&15, quad = lane>>4;
  int wr = w>>1, wc = w&1;
  int lg = lane>>3, pp = lane&7, px = pp ^ lg;
  int rowl = (w<<4) + (lg<<1) + (px>>2);             // 0..63 logical row
  int c4s = (px&3)*8;                                 // logical 16B chunk (shorts)
  int sdst = w*512 + lane*8;                          // linear LDS dest
  const unsigned short* pA0h = Ah + (long)(m0+rowl   )*lda + c4s;
  const unsigned short* pA1h = Ah + (long)(m0+rowl+64)*lda + c4s;
  const unsigned short* pA0l = Al + (long)(m0+rowl   )*lda + c4s;
  const unsigned short* pA1l = Al + (long)(m0+rowl+64)*lda + c4s;
  const unsigned short* pB0h = Bh + (long)(n0+rowl   )*ldb + c4s;
  const unsigned short* pB1h = Bh + (long)(n0+rowl+64)*ldb + c4s;
  const unsigned short* pB0l = Bl + (long)(n0+rowl   )*ldb + c4s;
  const unsigned short* pB1l = Bl + (long)(n0+rowl+64)*ldb + c4s;
  int fc = (((((qm&1)<<2)|quad) ^ (qm>>1))<<3);

  floatx4 acc[4][4];
  #pragma unroll
  for(int m=0;m<4;m++)
    #pragma unroll
    for(int n=0;n<4;n++) acc[m][n] = (floatx4){0.f,0.f,0.f,0.f};

  for(int k0=0;k0<K;k0+=32){
    __syncthreads();
    glds16(pA0h+k0, Ash+sdst); glds16(pA1h+k0, Ash+sdst+2048);
    glds16(pA0l+k0, Asl+sdst); glds16(pA1l+k0, Asl+sdst+2048);
    glds16(pB0h+k0, Bsh+sdst); glds16(pB1h+k0, Bsh+sdst+2048);
    glds16(pB0l+k0, Bsl+sdst); glds16(pB1l+k0, Bsl+sdst+2048);
    __syncthreads();
    short8 ah[4], al[4], bh[4], bl[4];
    #pragma unroll
    for(int m=0;m<4;m++){
      int ar = (wr*32 + m*8 + (qm>>1))*64 + fc;
      ah[m] = *(const short8*)(Ash+ar);
      al[m] = *(const short8*)(Asl+ar);
    }
    #pragma unroll
    for(int n=0;n<4;n++){
      int br = (wc*32 + n*8 + (qm>>1))*64 + fc;
      bh[n] = *(const short8*)(Bsh+br);
      bl[n] = *(const short8*)(Bsl+br);
    }
    #pragma unroll
    for(int m=0;m<4;m++)
      #pragma unroll
      for(int n=0;n<4;n++){
        acc[m][n] = __builtin_amdgcn_mfma_f32_16x16x32_bf16(ah[m],bh[n],acc[m][n],0,0,0);
        acc[m][n] = __builtin_amdgcn_mfma_f32_16x16x32_bf16(ah[m],bl[n],acc[m][n],0,0,0);
        acc[m][n] = __builtin_amdgcn_mfma_f32_16x16x32_bf16(al[m],bh[n],acc[m][n],0,0,0);
      }
  }
  #pragma unroll
  for(int m=0;m<4;m++){
    int row = m0 + wr*64 + m*16 + quad*4;
    #pragma unroll
    for(int r=0;r<4;r++){
      long rb = (long)(row+r)*ldc + n0 + wc*64;
      #pragma unroll
      for(int n=0;n<4;n++){
        float v = acc[m][n][r];
        if(SPLIT){
          unsigned short hi,lo; splitbf(v,hi,lo);
          Ch[rb+n*16+qm]=hi; Cl[rb+n*16+qm]=lo;
        }else{
          Cf[rb+n*16+qm]=v;
        }
      }
    }
  }
}

// ---- merged output projections: dm@WoT -> dproj, dl@WodT -> dlproj ---------
// One 512-block launch; swz>>8 picks the projection (2 blocks/CU vs 1).
__global__ __launch_bounds__(256) void k_proj2(
    const unsigned short* __restrict__ dmh, const unsigned short* __restrict__ dml,
    const unsigned short* __restrict__ dlh, const unsigned short* __restrict__ dll,
    const unsigned short* __restrict__ WoTh, const unsigned short* __restrict__ WoTl,
    const unsigned short* __restrict__ WodTh, const unsigned short* __restrict__ WodTl,
    float* __restrict__ dproj, float* __restrict__ dlproj){
  __shared__ unsigned short Ash[128*32], Asl[128*32];
  __shared__ unsigned short Bsh[128*32], Bsl[128*32];
  int bid = blockIdx.x;
  int swz = (bid & 7)*64 + (bid >> 3);               // nwg=512 bijective
  int which = swz >> 8, rem = swz & 255;
  int bx = rem & 7, by = rem >> 3;
  int m0 = by*128, n0 = bx*128;
  const unsigned short* Ah = which ? dlh : dmh;
  const unsigned short* Al = which ? dll : dml;
  const unsigned short* Bh = which ? WodTh : WoTh;
  const unsigned short* Bl = which ? WodTl : WoTl;
  float* Cf = which ? dlproj : dproj;
  int tid = threadIdx.x, w = tid>>6, lane = tid&63;
  int qm = lane&15, quad = lane>>4;
  int wr = w>>1, wc = w&1;
  int lg = lane>>3, pp = lane&7, px = pp ^ lg;
  int rowl = (w<<4) + (lg<<1) + (px>>2);
  int c4s = (px&3)*8;
  int sdst = w*512 + lane*8;
  const unsigned short* pA0h = Ah + (long)(m0+rowl   )*1024 + c4s;
  const unsigned short* pA1h = Ah + (long)(m0+rowl+64)*1024 + c4s;
  const unsigned short* pA0l = Al + (long)(m0+rowl   )*1024 + c4s;
  const unsigned short* pA1l = Al + (long)(m0+rowl+64)*1024 + c4s;
  const unsigned short* pB0h = Bh + (long)(n0+rowl   )*1024 + c4s;
  const unsigned short* pB1h = Bh + (long)(n0+rowl+64)*1024 + c4s;
  const unsigned short* pB0l = Bl + (long)(n0+rowl   )*1024 + c4s;
  const unsigned short* pB1l = Bl + (long)(n0+rowl+64)*1024 + c4s;
  int fc = (((((qm&1)<<2)|quad) ^ (qm>>1))<<3);

  floatx4 acc[4][4];
  #pragma unroll
  for(int m=0;m<4;m++)
    #pragma unroll
    for(int n=0;n<4;n++) acc[m][n] = (floatx4){0.f,0.f,0.f,0.f};

  for(int k0=0;k0<1024;k0+=32){
    __syncthreads();
    glds16(pA0h+k0, Ash+sdst); glds16(pA1h+k0, Ash+sdst+2048);
    glds16(pA0l+k0, Asl+sdst); glds16(pA1l+k0, Asl+sdst+2048);
    glds16(pB0h+k0, Bsh+sdst); glds16(pB1h+k0, Bsh+sdst+2048);
    glds16(pB0l+k0, Bsl+sdst); glds16(pB1l+k0, Bsl+sdst+2048);
    __syncthreads();
    short8 ah[4], al[4], bh[4], bl[4];
    #pragma unroll
    for(int m=0;m<4;m++){
      int ar = (wr*32 + m*8 + (qm>>1))*64 + fc;
      ah[m] = *(const short8*)(Ash+ar);
      al[m] = *(const short8*)(Asl+ar);
    }
    #pragma unroll
    for(int n=0;n<4;n++){
      int br = (wc*32 + n*8 + (qm>>1))*64 + fc;
      bh[n] = *(const short8*)(Bsh+br);
      bl[n] = *(const short8*)(Bsl+br);
    }
    #pragma unroll
    for(int m=0;m<4;m++)
      #pragma unroll
      for(int n=0;n<4;n++){
        acc[m][n] = __builtin_amdgcn_mfma_f32_16x16x32_bf16(ah[m],bh[n],acc[m][n],0,0,0);
        acc[m][n] = __builtin_amdgcn_mfma_f32_16x16x32_bf16(ah[m],bl[n],acc[m][n],0,0,0);
        acc[m][n] = __builtin_amdgcn_mfma_f32_16x16x32_bf16(al[m],bh[n],acc[m][n],0,0,0);
      }
  }
  #pragma unroll
  for(int m=0;m<4;m++){
    int row = m0 + wr*64 + m*16 + quad*4;
    #pragma unroll
    for(int r=0;r<4;r++){
      long rb = (long)(row+r)*1024 + n0 + wc*64;
      #pragma unroll
      for(int n=0;n<4;n++)
        Cf[rb+n*16+qm] = acc[m][n][r];
    }
  }
}

// ---- gate: softmax(h1 @ w_gate) (h1 split, wg fp32) ------------------------
__global__ __launch_bounds__(256) void k_gate(
    const unsigned short* __restrict__ hh, const unsigned short* __restrict__ hl,
    const float* __restrict__ wg, float* __restrict__ gates){
  int token = blockIdx.x*4 + (threadIdx.x>>6);
  int lane = threadIdx.x&63;
  long hb = (long)token*DMODEL + lane*16;
  const float* w = wg + lane*16*2;
  float s0=0.f, s1=0.f;
  for(int i=0;i<16;i++){
    float hv = bf2f(hh[hb+i]) + bf2f(hl[hb+i]);
    s0 += hv*w[2*i]; s1 += hv*w[2*i+1];
  }
  for(int off=32;off;off>>=1){ s0+=__shfl_down(s0,off,64); s1+=__shfl_down(s1,off,64); }
  if(lane==0){
    float m=fmaxf(s0,s1), e0=__expf(s0-m), e1=__expf(s1-m), inv=1.f/(e0+e1);
    gates[token*2]=e0*inv; gates[token*2+1]=e1*inv;
  }
}

// ---- flash attention v3: K/V staged in LDS (XOR-swizzled), shared by waves -
__global__ __launch_bounds__(256) void k_attn_flash3(
    const unsigned short* __restrict__ qh, const unsigned short* __restrict__ qlp,
    const unsigned short* __restrict__ vth, const unsigned short* __restrict__ vtl,
    const unsigned long long* __restrict__ mp, unsigned short* __restrict__ dmh,
    unsigned short* __restrict__ dml){
  __shared__ unsigned short Ksh[64*64], Ksl[64*64];     // 16KB
  __shared__ unsigned short Vsh[64*64], Vsl[64*64];     // 16KB
  __shared__ unsigned short PWh[4*16*64], PWl[4*16*64]; // 16KB (swizzled)
  int bh = blockIdx.y, b = bh>>4, h = bh&15;
  int tid = threadIdx.x, w = tid>>6, lane = tid&63;
  int qm = lane&15, quad = (lane>>4)&3;
  int q0 = blockIdx.x*64 + w*16;
  long qrow = (long)(b*SEQ+q0+qm)*6144 + h*DK;
  short8 a_qh0 = *(const short8*)(qh +qrow+quad*8);
  short8 a_qh1 = *(const short8*)(qh +qrow+32+quad*8);
  short8 a_ql0 = *(const short8*)(qlp+qrow+quad*8);
  short8 a_ql1 = *(const short8*)(qlp+qrow+32+quad*8);
  float m[4], l[4];
  floatx4 o0={0,0,0,0}, o1={0,0,0,0}, o2={0,0,0,0}, o3={0,0,0,0};
  #pragma unroll
  for(int r=0;r<4;r++){ m[r]=-3.0e38f; l[r]=0.f; }
  const unsigned long long* mrow = mp + ((long)b*SEQ + q0 + quad*4)*16;

  int r8 = lane>>3;                 // row within 8-row stripe
  int c8 = (lane&7) ^ r8;           // inverse-swizzled global chunk
  int d0 = w*512 + lane*8;          // LDS dest (shorts), linear per lane
  const unsigned short* pKh0 = qh  + (long)(b*SEQ + w*8 + r8)*6144 + 1024 + h*DK + c8*8;
  const unsigned short* pKl0 = qlp + (long)(b*SEQ + w*8 + r8)*6144 + 1024 + h*DK + c8*8;
  const unsigned short* pKh1 = pKh0 + 32L*6144;
  const unsigned short* pKl1 = pKl0 + 32L*6144;
  const unsigned short* pVh0 = vth + ((long)bh*DK + w*8 + r8)*SEQ + c8*8;
  const unsigned short* pVl0 = vtl + ((long)bh*DK + w*8 + r8)*SEQ + c8*8;
  const unsigned short* pVh1 = pVh0 + 32L*SEQ;
  const unsigned short* pVl1 = pVl0 + 32L*SEQ;
  int q7 = qm&7;

  for(int kt=0; kt<SEQ; kt+=64){
    __syncthreads();
    long ko = (long)kt*6144;
    glds16(pKh0+ko, Ksh+d0); glds16(pKh1+ko, Ksh+d0+2048);
    glds16(pKl0+ko, Ksl+d0); glds16(pKl1+ko, Ksl+d0+2048);
    glds16(pVh0+kt, Vsh+d0); glds16(pVh1+kt, Vsh+d0+2048);
    glds16(pVl0+kt, Vsl+d0); glds16(pVl1+kt, Vsl+d0+2048);
    __syncthreads();

    int wd = kt>>6;
    unsigned long long mws[4] = {mrow[wd], mrow[16+wd], mrow[32+wd], mrow[48+wd]};
    floatx4 s[4];
    #pragma unroll
    for(int st=0;st<4;st++){
      int krow = (st*16+qm)*64;
      short8 kh0 = *(const short8*)(Ksh + krow + ((quad    ^q7)<<3));
      short8 kh1 = *(const short8*)(Ksh + krow + (((4|quad)^q7)<<3));
      short8 kl0 = *(const short8*)(Ksl + krow + ((quad    ^q7)<<3));
      short8 kl1 = *(const short8*)(Ksl + krow + (((4|quad)^q7)<<3));
      floatx4 acc = {0,0,0,0};
      acc = __builtin_amdgcn_mfma_f32_16x16x32_bf16(a_qh0,kh0,acc,0,0,0);
      acc = __builtin_amdgcn_mfma_f32_16x16x32_bf16(a_qh1,kh1,acc,0,0,0);
      acc = __builtin_amdgcn_mfma_f32_16x16x32_bf16(a_qh0,kl0,acc,0,0,0);
      acc = __builtin_amdgcn_mfma_f32_16x16x32_bf16(a_qh1,kl1,acc,0,0,0);
      acc = __builtin_amdgcn_mfma_f32_16x16x32_bf16(a_ql0,kh0,acc,0,0,0);
      acc = __builtin_amdgcn_mfma_f32_16x16x32_bf16(a_ql1,kh1,acc,0,0,0);
      s[st] = acc;
    }
    #pragma unroll
    for(int r=0;r<4;r++){
      float v0 = ((mws[r]>>(   qm))&1) ? s[0][r]*0.125f : -1e9f;
      float v1 = ((mws[r]>>(16+qm))&1) ? s[1][r]*0.125f : -1e9f;
      float v2 = ((mws[r]>>(32+qm))&1) ? s[2][r]*0.125f : -1e9f;
      float v3 = ((mws[r]>>(48+qm))&1) ? s[3][r]*0.125f : -1e9f;
      float tm = fmaxf(fmaxf(v0,v1), fmaxf(v2,v3));
      tm = fmaxf(tm, __shfl_xor(tm,1,16));
      tm = fmaxf(tm, __shfl_xor(tm,2,16));
      tm = fmaxf(tm, __shfl_xor(tm,4,16));
      tm = fmaxf(tm, __shfl_xor(tm,8,16));
      float nm = fmaxf(m[r], tm);
      float al = __expf(m[r]-nm);
      m[r] = nm;
      float p0=__expf(v0-nm), p1=__expf(v1-nm), p2=__expf(v2-nm), p3=__expf(v3-nm);
      float rs = p0+p1+p2+p3;
      rs += __shfl_xor(rs,1,16); rs += __shfl_xor(rs,2,16);
      rs += __shfl_xor(rs,4,16); rs += __shfl_xor(rs,8,16);
      l[r] = l[r]*al + rs;
      o0[r]*=al; o1[r]*=al; o2[r]*=al; o3[r]*=al;
      int row = quad*4+r, rsw = row&7;
      int pb = w*1024 + row*64 + (qm&7);
      unsigned short hi,lo;
      splitbf(p0,hi,lo); PWh[pb + ((( (qm>>3))^rsw)<<3)]=hi; PWl[pb + ((( (qm>>3))^rsw)<<3)]=lo;
      splitbf(p1,hi,lo); PWh[pb + (((2|(qm>>3))^rsw)<<3)]=hi; PWl[pb + (((2|(qm>>3))^rsw)<<3)]=lo;
      splitbf(p2,hi,lo); PWh[pb + (((4|(qm>>3))^rsw)<<3)]=hi; PWl[pb + (((4|(qm>>3))^rsw)<<3)]=lo;
      splitbf(p3,hi,lo); PWh[pb + (((6|(qm>>3))^rsw)<<3)]=hi; PWl[pb + (((6|(qm>>3))^rsw)<<3)]=lo;
    }
    __builtin_amdgcn_wave_barrier();
    int prb = w*1024 + qm*64;
    short8 ph0 = *(const short8*)(PWh + prb + ((quad    ^q7)<<3));
    short8 ph1 = *(const short8*)(PWh + prb + (((4|quad)^q7)<<3));
    short8 pl0 = *(const short8*)(PWl + prb + ((quad    ^q7)<<3));
    short8 pl1 = *(const short8*)(PWl + prb + (((4|quad)^q7)<<3));
    __builtin_amdgcn_wave_barrier();
    {
      int c0 = (quad    ^q7)<<3;
      int c1 = ((4|quad)^q7)<<3;
      int vr0 = (0*16+qm)*64, vr1 = (1*16+qm)*64, vr2 = (2*16+qm)*64, vr3 = (3*16+qm)*64;
      short8 v0h0=*(const short8*)(Vsh+vr0+c0), v0h1=*(const short8*)(Vsh+vr0+c1);
      short8 v1h0=*(const short8*)(Vsh+vr1+c0), v1h1=*(const short8*)(Vsh+vr1+c1);
      short8 v2h0=*(const short8*)(Vsh+vr2+c0), v2h1=*(const short8*)(Vsh+vr2+c1);
      short8 v3h0=*(const short8*)(Vsh+vr3+c0), v3h1=*(const short8*)(Vsh+vr3+c1);
      short8 v0l0=*(const short8*)(Vsl+vr0+c0), v0l1=*(const short8*)(Vsl+vr0+c1);
      short8 v1l0=*(const short8*)(Vsl+vr1+c0), v1l1=*(const short8*)(Vsl+vr1+c1);
      short8 v2l0=*(const short8*)(Vsl+vr2+c0), v2l1=*(const short8*)(Vsl+vr2+c1);
      short8 v3l0=*(const short8*)(Vsl+vr3+c0), v3l1=*(const short8*)(Vsl+vr3+c1);
      o0 = __builtin_amdgcn_mfma_f32_16x16x32_bf16(ph0,v0h0,o0,0,0,0);
      o0 = __builtin_amdgcn_mfma_f32_16x16x32_bf16(ph1,v0h1,o0,0,0,0);
      o0 = __builtin_amdgcn_mfma_f32_16x16x32_bf16(ph0,v0l0,o0,0,0,0);
      o0 = __builtin_amdgcn_mfma_f32_16x16x32_bf16(ph1,v0l1,o0,0,0,0);
      o0 = __builtin_amdgcn_mfma_f32_16x16x32_bf16(pl0,v0h0,o0,0,0,0);
      o0 = __builtin_amdgcn_mfma_f32_16x16x32_bf16(pl1,v0h1,o0,0,0,0);
      o1 = __builtin_amdgcn_mfma_f32_16x16x32_bf16(ph0,v1h0,o1,0,0,0);
      o1 = __builtin_amdgcn_mfma_f32_16x16x32_bf16(ph1,v1h1,o1,0,0,0);
      o1 = __builtin_amdgcn_mfma_f32_16x16x32_bf16(ph0,v1l0,o1,0,0,0);
      o1 = __builtin_amdgcn_mfma_f32_16x16x32_bf16(ph1,v1l1,o1,0,0,0);
      o1 = __builtin_amdgcn_mfma_f32_16x16x32_bf16(pl0,v1h0,o1,0,0,0);
      o1 = __builtin_amdgcn_mfma_f32_16x16x32_bf16(pl1,v1h1,o1,0,0,0);
      o2 = __builtin_amdgcn_mfma_f32_16x16x32_bf16(ph0,v2h0,o2,0,0,0);
      o2 = __builtin_amdgcn_mfma_f32_16x16x32_bf16(ph1,v2h1,o2,0,0,0);
      o2 = __builtin_amdgcn_mfma_f32_16x16x32_bf16(ph0,v2l0,o2,0,0,0);
      o2 = __builtin_amdgcn_mfma_f32_16x16x32_bf16(ph1,v2l1,o2,0,0,0);
      o2 = __builtin_amdgcn_mfma_f32_16x16x32_bf16(pl0,v2h0,o2,0,0,0);
      o2 = __builtin_amdgcn_mfma_f32_16x16x32_bf16(pl1,v2h1,o2,0,0,0);
      o3 = __builtin_amdgcn_mfma_f32_16x16x32_bf16(ph0,v3h0,o3,0,0,0);
      o3 = __builtin_amdgcn_mfma_f32_16x16x32_bf16(ph1,v3h1,o3,0,0,0);
      o3 = __builtin_amdgcn_mfma_f32_16x16x32_bf16(ph0,v3l0,o3,0,0,0);
      o3 = __builtin_amdgcn_mfma_f32_16x16x32_bf16(ph1,v3l1,o3,0,0,0);
      o3 = __builtin_amdgcn_mfma_f32_16x16x32_bf16(pl0,v3h0,o3,0,0,0);
      o3 = __builtin_amdgcn_mfma_f32_16x16x32_bf16(pl1,v3h1,o3,0,0,0);
    }
  }
  #pragma unroll
  for(int r=0;r<4;r++){
    float inv = 1.f/l[r];
    long rb = ((long)(b*SEQ + q0 + quad*4 + r))*DMODEL + h*DK;
    unsigned short hi,lo;
    splitbf(o0[r]*inv,hi,lo); dmh[rb+   qm]=hi; dml[rb+   qm]=lo;
    splitbf(o1[r]*inv,hi,lo); dmh[rb+16+qm]=hi; dml[rb+16+qm]=lo;
    splitbf(o2[r]*inv,hi,lo); dmh[rb+32+qm]=hi; dml[rb+32+qm]=lo;
    splitbf(o3[r]*inv,hi,lo); dmh[rb+48+qm]=hi; dml[rb+48+qm]=lo;
  }
}

// ---- delta ctx via MFMA + fused ksum ---------------------------------------
// ctx[bh] = kdT[bh] @ vdT[bh]^T over s (K=1024); ksum[bh][d] = sum_s relu(kd).
// kdT/vdT layout [bh][dk=64][s=1024] split planes. One block per bh, 4 waves.
__global__ __launch_bounds__(256) void k_delta_ctx2(
    const unsigned short* __restrict__ kdTh, const unsigned short* __restrict__ kdTl,
    const unsigned short* __restrict__ vdTh, const unsigned short* __restrict__ vdTl,
    float* __restrict__ ctx, float* __restrict__ ksum){
  int bh = blockIdx.x;
  int tid = threadIdx.x, w = tid>>6, lane = tid&63;
  int qm = lane&15, quad = lane>>4;
  long abase = ((long)bh*DK + w*16 + qm)*SEQ + quad*8;
  long bbase = ((long)bh*DK + qm)*SEQ + quad*8;
  floatx4 acc[4];
  #pragma unroll
  for(int n=0;n<4;n++) acc[n] = (floatx4){0.f,0.f,0.f,0.f};
  float ks = 0.f;
  #pragma unroll 2
  for(int s0=0;s0<SEQ;s0+=32){
    short8 ah = *(const short8*)(kdTh + abase + s0);
    short8 al = *(const short8*)(kdTl + abase + s0);
    #pragma unroll
    for(int j=0;j<8;j++)
      ks += fmaxf(bf2f((unsigned short)ah[j]) + bf2f((unsigned short)al[j]), 0.f);
    #pragma unroll
    for(int n=0;n<4;n++){
      short8 bh8 = *(const short8*)(vdTh + bbase + (long)n*16*SEQ + s0);
      short8 bl8 = *(const short8*)(vdTl + bbase + (long)n*16*SEQ + s0);
      acc[n] = __builtin_amdgcn_mfma_f32_16x16x32_bf16(ah,bh8,acc[n],0,0,0);
      acc[n] = __builtin_amdgcn_mfma_f32_16x16x32_bf16(ah,bl8,acc[n],0,0,0);
      acc[n] = __builtin_amdgcn_mfma_f32_16x16x32_bf16(al,bh8,acc[n],0,0,0);
    }
  }
  long cb = (long)bh*DK*DK;
  #pragma unroll
  for(int n=0;n<4;n++)
    #pragma unroll
    for(int r=0;r<4;r++)
      ctx[cb + (long)(w*16 + quad*4 + r)*DK + n*16 + qm] = acc[n][r];
  // ksum: lane (w,quad,qm) holds partial over s≡quad*8..quad*8+7 (mod 32);
  // reduce across quad (lane^16, lane^32), write from quad==0.
  ks += __shfl_xor(ks,16,64);
  ks += __shfl_xor(ks,32,64);
  if(quad==0) ksum[bh*DK + w*16 + qm] = ks;
}

// ---- delta: out = relu(qd)@ctx / z, split-bf16 output ----------------------
__global__ __launch_bounds__(256) void k_delta_out(
    const unsigned short* __restrict__ qh, const unsigned short* __restrict__ qlp,
    const float* __restrict__ ctx, const float* __restrict__ ksum,
    unsigned short* __restrict__ dlh, unsigned short* __restrict__ dll){
  int tok = blockIdx.x, b = tok>>10;
  int tid = threadIdx.x;
  __shared__ float ql[DMODEL];
  long sb = (long)tok*6144 + 3072;
  for(int c=tid;c<DMODEL;c+=256)
    ql[c] = fmaxf(bf2f(qh[sb+c]) + bf2f(qlp[sb+c]), 0.f);
  __syncthreads();
  int h = tid>>4, dg = (tid&15)*4;
  int bh = b*NHEAD + h;
  const float* C = ctx + (long)bh*DK*DK;
  const float* KS = ksum + bh*DK;
  float a0=0,a1=0,a2=0,a3=0,z=0;
  for(int d=0;d<DK;d++){
    float q = ql[h*DK + d];
    z += q * KS[d];
    const float* cr = C + d*DK + dg;
    a0 += q*cr[0]; a1 += q*cr[1]; a2 += q*cr[2]; a3 += q*cr[3];
  }
  float inv = 1.f/(z + 1e-6f);
  long db = (long)tok*DMODEL + h*DK + dg;
  unsigned short hi,lo;
  splitbf(a0*inv,hi,lo); dlh[db  ]=hi; dll[db  ]=lo;
  splitbf(a1*inv,hi,lo); dlh[db+1]=hi; dll[db+1]=lo;
  splitbf(a2*inv,hi,lo); dlh[db+2]=hi; dll[db+2]=lo;
  splitbf(a3*inv,hi,lo); dlh[db+3]=hi; dll[db+3]=lo;
}

// ---- fused: x1 = x+g0*dp+g1*dlp (fp32); h2=LN2(x1); router top2 ------------
__global__ __launch_bounds__(256) void k_comb_router(
    const float* __restrict__ x, const float* __restrict__ dp,
    const float* __restrict__ dlp, const float* __restrict__ gates,
    const float* __restrict__ g, const float* __restrict__ bb,
    const float* __restrict__ wr, unsigned short* __restrict__ h2b,
    float* __restrict__ topw, int* __restrict__ topi, int* __restrict__ counts){
  __shared__ float red[4];
  __shared__ float ered[4][8];
  int t = blockIdx.x, tid = threadIdx.x;
  float g0 = gates[t*2], g1 = gates[t*2+1];
  long base = (long)t*DMODEL + tid*4;
  floatx4 xv = *(const floatx4*)(x + base);
  float v[4];
  for(int i=0;i<4;i++) v[i] = xv[i] + g0*dp[base+i] + g1*dlp[base+i];
  float s = block_sum(v[0]+v[1]+v[2]+v[3], red);
  float mu = s*(1.f/DMODEL);
  float q=0.f; for(int i=0;i<4;i++){ float d=v[i]-mu; q+=d*d; }
  q = block_sum(q, red);
  float inv = rsqrtf(q*(1.f/DMODEL)+1e-5f);
  float a[8]; for(int e=0;e<8;e++) a[e]=0.f;
  for(int i=0;i<4;i++){
    int d = tid*4+i;
    float hv = (v[i]-mu)*inv*g[d] + bb[d];
    h2b[base+i] = f2bf(hv);
    const float* wrow = wr + (long)d*NEXP;
    for(int e=0;e<8;e++) a[e] += hv*wrow[e];
  }
  for(int off=32;off;off>>=1)
    for(int e=0;e<8;e++) a[e] += __shfl_down(a[e],off,64);
  int w = tid>>6;
  if((tid&63)==0) for(int e=0;e<8;e++) ered[w][e]=a[e];
  __syncthreads();
  if(tid==0){
    float lg[8];
    for(int e=0;e<8;e++) lg[e]=ered[0][e]+ered[1][e]+ered[2][e]+ered[3][e];
    int i0=0; for(int e=1;e<8;e++) if(lg[e]>lg[i0]) i0=e;
    int i1=-1; for(int e=0;e<8;e++){ if(e==i0) continue; if(i1<0||lg[e]>lg[i1]) i1=e; }
    float mm=fmaxf(lg[i0],lg[i1]), e0=__expf(lg[i0]-mm), e1=__expf(lg[i1]-mm), s2=1.f/(e0+e1);
    topw[t*2]=e0*s2; topw[t*2+1]=e1*s2;
    topi[t*2]=i0; topi[t*2+1]=i1;
    atomicAdd(&counts[i0],1); atomicAdd(&counts[i1],1);
  }
}

// ---- expert segment offsets + tile table (128-row tiles) -------------------
__global__ void k_meta(const int* __restrict__ counts, int* offs, int* tE,
                       int* tR0, int* tR1, int* ntp, int* cursor){
  if(threadIdx.x==0){
    int o=0, nt=0;
    for(int e=0;e<NEXP;e++){
      offs[e]=o; cursor[e]=0;
      int n=counts[e];
      for(int t=0;t<(n+127)/128;t++){ tE[nt]=e; tR0[nt]=o+t*128; tR1[nt]=o+n; nt++; }
      o+=n;
    }
    offs[NEXP]=o; ntp[0]=nt;
  }
}

// ---- scatter tokens into expert-sorted slots -------------------------------
__global__ __launch_bounds__(256) void k_scatter(
    const int* __restrict__ topi, const int* __restrict__ offs,
    int* cursor, int* perm, int* slotof){
  int token = blockIdx.x*256 + threadIdx.x;
  for(int k=0;k<2;k++){
    int e = topi[token*2+k];
    int pos = atomicAdd(&cursor[e],1);
    int slot = offs[e]+pos;
    perm[slot]=token; slotof[token*2+k]=slot;
  }
}

// ---- MoE GEMM, 128x256 tile + superrow XOR swizzle -------------------------
// 4 waves as 2Mx2N; each wave 64x128 = 4x8 frags => 32 MFMA per K-step
// (2x the 128^2 version per barrier pair). A: 2 glds, B: 4 glds per lane.
template<int GELU, int GATHER>
__global__ __launch_bounds__(256) void k_moe256(
    const unsigned short* __restrict__ A, const unsigned short* __restrict__ BtA,
    unsigned short* __restrict__ C, const int* __restrict__ perm,
    const int* __restrict__ ntp, const int* __restrict__ tE,
    const int* __restrict__ tR0, const int* __restrict__ tR1,
    int K, int N){
  int bz = blockIdx.y;
  if(bz >= ntp[0]) return;
  int e = tE[bz], r0t = tR0[bz], r1t = tR1[bz];
  __shared__ unsigned short As[128*32], Bs[256*32];
  int tid = threadIdx.x, w = tid>>6, lane = tid&63;
  int qm = lane&15, quad = lane>>4;
  int wr = w>>1, wc = w&1;
  int n0 = blockIdx.x*256;
  int lg = lane>>3, pp = lane&7, px = pp ^ lg;
  int rowl = (w<<4) + (lg<<1) + (px>>2);
  int c4s = (px&3)*8;
  int sdst = w*512 + lane*8;
  int fc = (((((qm&1)<<2)|quad) ^ (qm>>1))<<3);
  int gr0 = r0t + rowl, gr1 = gr0 + 64;
  int gc0 = gr0 < 8191 ? gr0 : 8191;
  int gc1 = gr1 < 8191 ? gr1 : 8191;
  const unsigned short *pA0, *pA1;
  if(GATHER){
    pA0 = A + (long)perm[gc0]*K + c4s;
    pA1 = A + (long)perm[gc1]*K + c4s;
  }else{
    pA0 = A + (long)gc0*K + c4s;
    pA1 = A + (long)gc1*K + c4s;
  }
  const unsigned short* Bt = BtA + (long)e*N*K;
  const unsigned short* pB0 = Bt + (long)(n0+rowl    )*K + c4s;
  const unsigned short* pB1 = Bt + (long)(n0+rowl+64 )*K + c4s;
  const unsigned short* pB2 = Bt + (long)(n0+rowl+128)*K + c4s;
  const unsigned short* pB3 = Bt + (long)(n0+rowl+192)*K + c4s;

  floatx4 acc[4][8];
  #pragma unroll
  for(int m=0;m<4;m++)
    #pragma unroll
    for(int n=0;n<8;n++) acc[m][n] = (floatx4){0.f,0.f,0.f,0.f};

  for(int k0=0;k0<K;k0+=32){
    __syncthreads();
    glds16(pA0+k0, As+sdst); glds16(pA1+k0, As+sdst+2048);
    glds16(pB0+k0, Bs+sdst);      glds16(pB1+k0, Bs+sdst+2048);
    glds16(pB2+k0, Bs+sdst+4096); glds16(pB3+k0, Bs+sdst+6144);
    __syncthreads();
    short8 af[4], bf[8];
    #pragma unroll
    for(int m=0;m<4;m++)
      af[m] = *(const short8*)(As + (wr*32 + m*8 + (qm>>1))*64 + fc);
    #pragma unroll
    for(int n=0;n<8;n++)
      bf[n] = *(const short8*)(Bs + (wc*64 + n*8 + (qm>>1))*64 + fc);
    #pragma unroll
    for(int m=0;m<4;m++)
      #pragma unroll
      for(int n=0;n<8;n++)
        acc[m][n] = __builtin_amdgcn_mfma_f32_16x16x32_bf16(af[m],bf[n],acc[m][n],0,0,0);
  }
  #pragma unroll
  for(int m=0;m<4;m++){
    int row = r0t + wr*64 + m*16 + quad*4;
    #pragma unroll
    for(int r=0;r<4;r++){
      if(row+r < r1t){
        long rb = (long)(row+r)*N + n0 + wc*128;
        #pragma unroll
        for(int n=0;n<8;n++){
          float xx = acc[m][n][r];
          if(GELU) xx = 0.5f*xx*(1.f+erff(xx*0.70710678f));
          C[rb+n*16+qm] = f2bf(xx);
        }
      }
    }
  }
}

// ---- final: out = x + g0*dp + g1*dlp + w0*Y[s0] + w1*Y[s1] (fp32) ----------
__global__ __launch_bounds__(256) void k_final(
    const float* __restrict__ x, const float* __restrict__ dp,
    const float* __restrict__ dlp, const float* __restrict__ gates,
    const unsigned short* __restrict__ Y, const int* __restrict__ slotof,
    const float* __restrict__ topw, float* __restrict__ out){
  int t = blockIdx.x, tid = threadIdx.x;
  int s0 = slotof[t*2], s1 = slotof[t*2+1];
  float w0 = topw[t*2], w1 = topw[t*2+1];
  float g0 = gates[t*2], g1 = gates[t*2+1];
  long base = (long)t*DMODEL + tid*4;
  const unsigned short* y0 = Y + (long)s0*DMODEL + tid*4;
  const unsigned short* y1 = Y + (long)s1*DMODEL + tid*4;
  floatx4 xv = *(const floatx4*)(x + base);
  for(int i=0;i<4;i++)
    out[base+i] = xv[i] + g0*dp[base+i] + g1*dlp[base+i]
                        + w0*bf2f(y0[i]) + w1*bf2f(y1[i]);
}

// ===========================================================================
extern "C" void kernel_launch(void* const* d_in, const int* in_sizes, int n_in,
                              void* d_out, int out_size, void* d_ws, size_t ws_size,
                              hipStream_t stream){
  const float* x    = (const float*)d_in[0];
  const int*   mask = (const int*)d_in[1];
  const float* ln1g = (const float*)d_in[2];
  const float* ln1b = (const float*)d_in[3];
  const float* wq   = (const float*)d_in[4];
  const float* wk   = (const float*)d_in[5];
  const float* wv   = (const float*)d_in[6];
  const float* wo   = (const float*)d_in[7];
  const float* wqd  = (const float*)d_in[8];
  const float* wkd  = (const float*)d_in[9];
  const float* wvd  = (const float*)d_in[10];
  const float* wod  = (const float*)d_in[11];
  const float* wg   = (const float*)d_in[12];
  const float* ln2g = (const float*)d_in[13];
  const float* ln2b = (const float*)d_in[14];
  const float* wr   = (const float*)d_in[15];
  const float* ew1  = (const float*)d_in[16];
  const float* ew2  = (const float*)d_in[17];
  float* out = (float*)d_out;

  char* p = (char*)d_ws;
  auto alloc = [&](size_t b)->char*{ char* r=p; p += (b + 255) & ~(size_t)255; return r; };
  unsigned short* WtAllh = (unsigned short*)alloc(6144L*1024*2);
  unsigned short* WtAlll = (unsigned short*)alloc(6144L*1024*2);
  unsigned short* WoTh   = (unsigned short*)alloc(1024L*1024*2);
  unsigned short* WoTl   = (unsigned short*)alloc(1024L*1024*2);
  unsigned short* WodTh  = (unsigned short*)alloc(1024L*1024*2);
  unsigned short* WodTl  = (unsigned short*)alloc(1024L*1024*2);
  unsigned short* eW1T   = (unsigned short*)alloc(8L*2048*1024*2);
  unsigned short* eW2T   = (unsigned short*)alloc(8L*1024*2048*2);
  unsigned short* h1h    = (unsigned short*)alloc(4096L*1024*2);  // later vTh
  unsigned short* h1l    = (unsigned short*)alloc(4096L*1024*2);  // later vTl
  unsigned short* qkvh   = (unsigned short*)alloc(4096L*6144*2);  // later dproj+dlproj (fp32)
  unsigned short* qkvl   = (unsigned short*)alloc(4096L*6144*2);  // later H
  unsigned short* dmh    = (unsigned short*)alloc(4096L*1024*2);  // first vdTh, then attn out, then Y
  unsigned short* dml    = (unsigned short*)alloc(4096L*1024*2);  // first vdTl
  unsigned short* dlh    = (unsigned short*)alloc(4096L*1024*2);  // first kdTh
  unsigned short* dll    = (unsigned short*)alloc(4096L*1024*2);  // first kdTl
  float* ctx   = (float*)alloc(64L*64*64*4);
  float* ksum  = (float*)alloc(64L*64*4);
  float* gates = (float*)alloc(4096L*2*4);
  unsigned short* h2b = (unsigned short*)alloc(4096L*1024*2);
  float* topw = (float*)alloc(4096L*2*4);
  int* topi   = (int*)alloc(4096L*2*4);
  int* slotof = (int*)alloc(4096L*2*4);
  int* perm   = (int*)alloc(8192L*4);
  int* counts = (int*)alloc(64*4);
  int* cursor = (int*)alloc(64*4);
  int* offs   = (int*)alloc(64*4);
  int* ntp    = (int*)alloc(64*4);
  int* tE     = (int*)alloc(MAXTILE*4);
  int* tR0    = (int*)alloc(MAXTILE*4);
  int* tR1    = (int*)alloc(MAXTILE*4);
  unsigned long long* mpack = (unsigned long long*)alloc(4L*1024*16*8);
  if ((size_t)(p - (char*)d_ws) > ws_size) return;  // ws too small -> absmax==ref max

  unsigned short* vTh = h1h;                    // after h1 consumed (qkv gemm + gate)
  unsigned short* vTl = h1l;
  unsigned short* kdTh = dlh;                   // until delta_out overwrites
  unsigned short* kdTl = dll;
  unsigned short* vdTh = dmh;                   // consumed by ctx2 BEFORE attn writes dmh
  unsigned short* vdTl = dml;
  float* dproj  = (float*)qkvh;                 // after qkv consumed (attn+delta)
  float* dlproj = (float*)(qkvh + 8388608);     // second 16.8MB of qkvh region
  unsigned short* H = qkvl;                     // after qkv consumed
  unsigned short* Y = dmh;                      // spans dmh+dml (16.8MB), after projections read dm

  dim3 tb(256);
  // mask bit-pack (independent)
  k_maskpack<<<16384,tb,0,stream>>>(mask, mpack);
  // weight transposes: attention weights split, MoE weights single bf16
  k_transpose_f2<<<dim3(32,32,1),tb,0,stream>>>(wq,  WtAllh+0L*1048576, WtAlll+0L*1048576, 1024,1024, 0,0);
  k_transpose_f2<<<dim3(32,32,1),tb,0,stream>>>(wk,  WtAllh+1L*1048576, WtAlll+1L*1048576, 1024,1024, 0,0);
  k_transpose_f2<<<dim3(32,32,1),tb,0,stream>>>(wv,  WtAllh+2L*1048576, WtAlll+2L*1048576, 1024,1024, 0,0);
  k_transpose_f2<<<dim3(32,32,1),tb,0,stream>>>(wqd, WtAllh+3L*1048576, WtAlll+3L*1048576, 1024,1024, 0,0);
  k_transpose_f2<<<dim3(32,32,1),tb,0,stream>>>(wkd, WtAllh+4L*1048576, WtAlll+4L*1048576, 1024,1024, 0,0);
  k_transpose_f2<<<dim3(32,32,1),tb,0,stream>>>(wvd, WtAllh+5L*1048576, WtAlll+5L*1048576, 1024,1024, 0,0);
  k_transpose_f2<<<dim3(32,32,1),tb,0,stream>>>(wo,  WoTh,  WoTl,  1024,1024, 0,0);
  k_transpose_f2<<<dim3(32,32,1),tb,0,stream>>>(wod, WodTh, WodTl, 1024,1024, 0,0);
  k_transpose_f<<<dim3(64,32,8),tb,0,stream>>>(ew1, eW1T, 2048,1024, 1024L*2048, 2048L*1024);
  k_transpose_f<<<dim3(32,64,8),tb,0,stream>>>(ew2, eW2T, 1024,2048, 2048L*1024, 1024L*2048);
  // LN1 -> h1 split
  k_ln1<<<4096,tb,0,stream>>>(x, ln1g, ln1b, h1h, h1l);
  // qkv: all 6 projections, split in/out. grid 48x32 tiles of 128, linear+swz.
  k_gemm128_ss<1><<<dim3(1536),tb,0,stream>>>(h1h,h1l, WtAllh,WtAlll, qkvh,qkvl,nullptr,
                                              1024, 1024, 1024, 6144, 48);
  // gate (fp32 path)
  k_gate<<<1024,tb,0,stream>>>(h1h, h1l, wg, gates);
  // transposed slices: v (attn), kd, vd (delta; vd aliases dmh/dml) — fused
  k_vt3<<<dim3(32,6,64),tb,0,stream>>>(qkvh, qkvl, vTh, vTl, kdTh, kdTl, vdTh, vdTl);
  // delta ctx (+fused ksum) FIRST (consume vdT before attention overwrites dmh/dml)
  k_delta_ctx2<<<64,tb,0,stream>>>(kdTh, kdTl, vdTh, vdTl, ctx, ksum);
  // flash attention v3 (split precision, LDS-staged K/V) -> dmh/dml
  k_attn_flash3<<<dim3(16,64),tb,0,stream>>>(qkvh, qkvl, vTh, vTl, mpack, dmh, dml);
  // delta out (overwrites kdT buffers dlh/dll)
  k_delta_out<<<4096,tb,0,stream>>>(qkvh, qkvl, ctx, ksum, dlh, dll);
  // merged output projections -> fp32 (512 blocks = 2/CU)
  k_proj2<<<dim3(512),tb,0,stream>>>(dmh,dml, dlh,dll, WoTh,WoTl, WodTh,WodTl,
                                     dproj, dlproj);
  // residual + gate-mix + LN2 + router (all fp32)
  hipMemsetAsync(counts, 0, NEXP*sizeof(int), stream);
  k_comb_router<<<4096,tb,0,stream>>>(x, dproj, dlproj, gates, ln2g, ln2b, wr,
                                      h2b, topw, topi, counts);
  k_meta<<<1,64,0,stream>>>(counts, offs, tE, tR0, tR1, ntp, cursor);
  k_scatter<<<16,tb,0,stream>>>(topi, offs, cursor, perm, slotof);
  // expert GEMMs (128-row tiles; 256-wide N tiles)
  k_moe256<1,1><<<dim3(8,72),tb,0,stream>>>(h2b, eW1T, H, perm, ntp, tE, tR0, tR1,
                                            1024, 2048);
  k_moe256<0,0><<<dim3(4,72),tb,0,stream>>>(H, eW2T, Y, perm, ntp, tE, tR0, tR1,
                                            2048, 1024);
  // final residual combine
  k_final<<<4096,tb,0,stream>>>(x, dproj, dlproj, gates, Y, slotof, topw, out);
}

// Round 6
// 1003.121 us; speedup vs baseline: 1.2290x; 1.2290x over previous
//
#include <hip/hip_runtime.h>
#include <stdint.h>

// ---------------------------------------------------------------------------
// Qwen3.5-style layer on MI355X. fp32 in/out. Pre-router chain computed in
// split-bf16 (hi/lo) 3-pass MFMA => ~fp32 precision so the discrete top-2
// expert selection matches the fp32 reference. MoE GEMMs single bf16.
// R5: all GEMMs on m97 structure (128x128, global_load_lds w16, XCD swizzle).
// R6: attention K/V staged in LDS, XOR-swizzled, 2-barrier loop.
// R7/R8: GEMM LDS superrow-XOR swizzle (bank conflicts -> 0); delta ctx via
//     MFMA; vdT aliases dmh/dml (ws budget).
// R9: fused vt3 / ksum-in-ctx2 / merged proj2 (kept). moe256 REGRESSED:
//     acc[4][8] = 264 regs/wave -> 1 block/CU -> latency-exposed (221us).
// R10: revert MoE GEMMs to 128x128 (152 regs/wave, 3 blocks/CU). Occupancy
//     beats per-barrier MFMA density when latency-bound (m132 lesson).
// ---------------------------------------------------------------------------

typedef __attribute__((ext_vector_type(8))) short short8;   // 8 bf16 = 16B
typedef __attribute__((ext_vector_type(4))) float floatx4;

#define DMODEL 1024
#define SEQ    1024
#define NHEAD  16
#define DK     64
#define DFF    2048
#define NEXP   8
#define MAXTILE 144

__device__ __forceinline__ float bf2f(unsigned short h){
  union{unsigned u;float f;}v; v.u=((unsigned)h)<<16; return v.f;
}
__device__ __forceinline__ unsigned short f2bf(float f){
  union{float f;unsigned u;}v; v.f=f;
  unsigned r=(v.u + 0x7FFFu + ((v.u>>16)&1u))>>16; return (unsigned short)r;
}
__device__ __forceinline__ void splitbf(float v, unsigned short& hi, unsigned short& lo){
  hi = f2bf(v); lo = f2bf(v - bf2f(hi));
}

// async global->LDS, 16B per lane. LDS dest is wave-uniform base + lane*16.
__device__ __forceinline__ void glds16(const unsigned short* g, unsigned short* l){
  __builtin_amdgcn_global_load_lds(
      (const __attribute__((address_space(1))) void*)g,
      (__attribute__((address_space(3))) void*)l, 16, 0, 0);
}

__device__ __forceinline__ float block_sum(float v, float* red){
  for(int off=32;off;off>>=1) v += __shfl_down(v,off,64);
  int w = threadIdx.x>>6;
  __syncthreads();
  if((threadIdx.x&63)==0) red[w]=v;
  __syncthreads();
  return red[0]+red[1]+red[2]+red[3];
}

// ---- pack mask to bits: one wave per 64-int chunk --------------------------
__global__ __launch_bounds__(256) void k_maskpack(
    const int* __restrict__ mask, unsigned long long* __restrict__ mp){
  int gw = blockIdx.x*4 + (threadIdx.x>>6);
  int lane = threadIdx.x&63;
  unsigned long long bm = __ballot(mask[(long)gw*64 + lane] != 0);
  if(lane==0) mp[gw]=bm;
}

// ---- transpose fp32 -> split bf16 planes: dst[c][r] = src[r][c] ------------
__global__ __launch_bounds__(256) void k_transpose_f2(
    const float* __restrict__ src, unsigned short* __restrict__ dh,
    unsigned short* __restrict__ dl, long srs, long drs, long sbs, long dbs){
  __shared__ float t[32][33];
  src += (long)blockIdx.z*sbs; dh += (long)blockIdx.z*dbs; dl += (long)blockIdx.z*dbs;
  int c0 = blockIdx.x*32, r0 = blockIdx.y*32;
  int tx = threadIdx.x & 31, ty = threadIdx.x >> 5;
  for(int i=0;i<32;i+=8)
    t[ty+i][tx] = src[(long)(r0+ty+i)*srs + (c0+tx)];
  __syncthreads();
  for(int i=0;i<32;i+=8){
    unsigned short hi,lo; splitbf(t[tx][ty+i],hi,lo);
    long idx = (long)(c0+ty+i)*drs + (r0+tx);
    dh[idx]=hi; dl[idx]=lo;
  }
}

// ---- transpose fp32 -> single bf16 (MoE weights) ---------------------------
__global__ __launch_bounds__(256) void k_transpose_f(
    const float* __restrict__ src, unsigned short* __restrict__ dst,
    long srs, long drs, long sbs, long dbs){
  __shared__ float t[32][33];
  src += (long)blockIdx.z*sbs; dst += (long)blockIdx.z*dbs;
  int c0 = blockIdx.x*32, r0 = blockIdx.y*32;
  int tx = threadIdx.x & 31, ty = threadIdx.x >> 5;
  for(int i=0;i<32;i+=8)
    t[ty+i][tx] = src[(long)(r0+ty+i)*srs + (c0+tx)];
  __syncthreads();
  for(int i=0;i<32;i+=8)
    dst[(long)(c0+ty+i)*drs + (r0+tx)] = f2bf(t[tx][ty+i]);
}

// ---- vT3: 3 slices (v, kd, vd), both planes, all (b,h) in one launch -------
// blockIdx.y in [0,6): slice = y>>1, d0 = (y&1)*32. dst[bh][dk][s].
__global__ __launch_bounds__(256) void k_vt3(
    const unsigned short* __restrict__ qh, const unsigned short* __restrict__ ql,
    unsigned short* __restrict__ vTh, unsigned short* __restrict__ vTl,
    unsigned short* __restrict__ kdTh, unsigned short* __restrict__ kdTl,
    unsigned short* __restrict__ vdTh, unsigned short* __restrict__ vdTl){
  __shared__ unsigned short th[32][33], tl[32][33];
  int z = blockIdx.z, b = z>>4, h = z&15;
  int slice = blockIdx.y >> 1;
  long coff = (slice==0) ? 2048 : (slice==1 ? 4096 : 5120);
  unsigned short* dh = (slice==0) ? vTh : (slice==1 ? kdTh : vdTh);
  unsigned short* dl = (slice==0) ? vTl : (slice==1 ? kdTl : vdTl);
  int s0 = blockIdx.x*32, d0 = (blockIdx.y&1)*32;
  int tx = threadIdx.x & 31, ty = threadIdx.x >> 5;
  for(int i=0;i<32;i+=8){
    long src = (long)(b*SEQ + s0+ty+i)*6144 + coff + h*DK + d0+tx;
    th[ty+i][tx] = qh[src]; tl[ty+i][tx] = ql[src];
  }
  __syncthreads();
  for(int i=0;i<32;i+=8){
    long dst = ((long)z*DK + d0+ty+i)*SEQ + s0+tx;
    dh[dst] = th[tx][ty+i]; dl[dst] = tl[tx][ty+i];
  }
}

// ---- LayerNorm 1: fp32 x -> split bf16 h1 ----------------------------------
__global__ __launch_bounds__(256) void k_ln1(
    const float* __restrict__ x, const float* __restrict__ g,
    const float* __restrict__ b, unsigned short* __restrict__ oh,
    unsigned short* __restrict__ ol){
  __shared__ float red[4];
  int t = blockIdx.x, tid = threadIdx.x;
  long base = (long)t*DMODEL + tid*4;
  floatx4 xv = *(const floatx4*)(x + base);
  float v[4] = {xv[0], xv[1], xv[2], xv[3]};
  float s = block_sum(v[0]+v[1]+v[2]+v[3], red);
  float mu = s * (1.f/DMODEL);
  float q=0.f;
  for(int i=0;i<4;i++){ float d=v[i]-mu; q+=d*d; }
  q = block_sum(q, red);
  float inv = rsqrtf(q*(1.f/DMODEL) + 1e-5f);
  for(int i=0;i<4;i++){
    int d = tid*4+i;
    unsigned short hi,lo; splitbf((v[i]-mu)*inv*g[d] + b[d], hi, lo);
    oh[base+i]=hi; ol[base+i]=lo;
  }
}

// ---- split GEMM, m97 structure + superrow XOR swizzle ----------------------
// LDS tile [128 rows][32 shorts] viewed as [64 superrows][8 chunks of 16B].
// Logical (row, c4) stored at physical chunk p = ((row&1)*4|c4) ^ ((row>>1)&7).
// Staging keeps LINEAR glds dest (lane*16B) and permutes the GLOBAL source;
// reads apply the same XOR => 2 lanes/bank-quad (free) instead of 8-way.
template<int SPLIT>
__global__ __launch_bounds__(256) void k_gemm128_ss(
    const unsigned short* __restrict__ Ah, const unsigned short* __restrict__ Al,
    const unsigned short* __restrict__ Bh, const unsigned short* __restrict__ Bl,
    unsigned short* __restrict__ Ch, unsigned short* __restrict__ Cl,
    float* __restrict__ Cf, int K, int lda, int ldb, int ldc, int gridN){
  __shared__ unsigned short Ash[128*32], Asl[128*32];
  __shared__ unsigned short Bsh[128*32], Bsl[128*32];
  int nwg = gridDim.x, bid = blockIdx.x;
  int swz = (bid & 7)*(nwg >> 3) + (bid >> 3);       // XCD-contiguous chunks
  int bx = swz % gridN, by = swz / gridN;
  int m0 = by*128, n0 = bx*128;
  int tid = threadIdx.x, w = tid>>6, lane = tid&63;
  int qm = lane&15, quad = lane>>4;
  int wr = w>>1, wc = w&1;
  int lg = lane>>3, pp = lane&7, px = pp ^ lg;
  int rowl = (w<<4) + (lg<<1) + (px>>2);             // 0..63 logical row
  int c4s = (px&3)*8;                                 // logical 16B chunk (shorts)
  int sdst = w*512 + lane*8;                          // linear LDS dest
  const unsigned short* pA0h = Ah + (long)(m0+rowl   )*lda + c4s;
  const unsigned short* pA1h = Ah + (long)(m0+rowl+64)*lda + c4s;
  const unsigned short* pA0l = Al + (long)(m0+rowl   )*lda + c4s;
  const unsigned short* pA1l = Al + (long)(m0+rowl+64)*lda + c4s;
  const unsigned short* pB0h = Bh + (long)(n0+rowl   )*ldb + c4s;
  const unsigned short* pB1h = Bh + (long)(n0+rowl+64)*ldb + c4s;
  const unsigned short* pB0l = Bl + (long)(n0+rowl   )*ldb + c4s;
  const unsigned short* pB1l = Bl + (long)(n0+rowl+64)*ldb + c4s;
  int fc = (((((qm&1)<<2)|quad) ^ (qm>>1))<<3);

  floatx4 acc[4][4];
  #pragma unroll
  for(int m=0;m<4;m++)
    #pragma unroll
    for(int n=0;n<4;n++) acc[m][n] = (floatx4){0.f,0.f,0.f,0.f};

  for(int k0=0;k0<K;k0+=32){
    __syncthreads();
    glds16(pA0h+k0, Ash+sdst); glds16(pA1h+k0, Ash+sdst+2048);
    glds16(pA0l+k0, Asl+sdst); glds16(pA1l+k0, Asl+sdst+2048);
    glds16(pB0h+k0, Bsh+sdst); glds16(pB1h+k0, Bsh+sdst+2048);
    glds16(pB0l+k0, Bsl+sdst); glds16(pB1l+k0, Bsl+sdst+2048);
    __syncthreads();
    short8 ah[4], al[4], bh[4], bl[4];
    #pragma unroll
    for(int m=0;m<4;m++){
      int ar = (wr*32 + m*8 + (qm>>1))*64 + fc;
      ah[m] = *(const short8*)(Ash+ar);
      al[m] = *(const short8*)(Asl+ar);
    }
    #pragma unroll
    for(int n=0;n<4;n++){
      int br = (wc*32 + n*8 + (qm>>1))*64 + fc;
      bh[n] = *(const short8*)(Bsh+br);
      bl[n] = *(const short8*)(Bsl+br);
    }
    #pragma unroll
    for(int m=0;m<4;m++)
      #pragma unroll
      for(int n=0;n<4;n++){
        acc[m][n] = __builtin_amdgcn_mfma_f32_16x16x32_bf16(ah[m],bh[n],acc[m][n],0,0,0);
        acc[m][n] = __builtin_amdgcn_mfma_f32_16x16x32_bf16(ah[m],bl[n],acc[m][n],0,0,0);
        acc[m][n] = __builtin_amdgcn_mfma_f32_16x16x32_bf16(al[m],bh[n],acc[m][n],0,0,0);
      }
  }
  #pragma unroll
  for(int m=0;m<4;m++){
    int row = m0 + wr*64 + m*16 + quad*4;
    #pragma unroll
    for(int r=0;r<4;r++){
      long rb = (long)(row+r)*ldc + n0 + wc*64;
      #pragma unroll
      for(int n=0;n<4;n++){
        float v = acc[m][n][r];
        if(SPLIT){
          unsigned short hi,lo; splitbf(v,hi,lo);
          Ch[rb+n*16+qm]=hi; Cl[rb+n*16+qm]=lo;
        }else{
          Cf[rb+n*16+qm]=v;
        }
      }
    }
  }
}

// ---- merged output projections: dm@WoT -> dproj, dl@WodT -> dlproj ---------
// One 512-block launch; swz>>8 picks the projection (2 blocks/CU vs 1).
__global__ __launch_bounds__(256) void k_proj2(
    const unsigned short* __restrict__ dmh, const unsigned short* __restrict__ dml,
    const unsigned short* __restrict__ dlh, const unsigned short* __restrict__ dll,
    const unsigned short* __restrict__ WoTh, const unsigned short* __restrict__ WoTl,
    const unsigned short* __restrict__ WodTh, const unsigned short* __restrict__ WodTl,
    float* __restrict__ dproj, float* __restrict__ dlproj){
  __shared__ unsigned short Ash[128*32], Asl[128*32];
  __shared__ unsigned short Bsh[128*32], Bsl[128*32];
  int bid = blockIdx.x;
  int swz = (bid & 7)*64 + (bid >> 3);               // nwg=512 bijective
  int which = swz >> 8, rem = swz & 255;
  int bx = rem & 7, by = rem >> 3;
  int m0 = by*128, n0 = bx*128;
  const unsigned short* Ah = which ? dlh : dmh;
  const unsigned short* Al = which ? dll : dml;
  const unsigned short* Bh = which ? WodTh : WoTh;
  const unsigned short* Bl = which ? WodTl : WoTl;
  float* Cf = which ? dlproj : dproj;
  int tid = threadIdx.x, w = tid>>6, lane = tid&63;
  int qm = lane&15, quad = lane>>4;
  int wr = w>>1, wc = w&1;
  int lg = lane>>3, pp = lane&7, px = pp ^ lg;
  int rowl = (w<<4) + (lg<<1) + (px>>2);
  int c4s = (px&3)*8;
  int sdst = w*512 + lane*8;
  const unsigned short* pA0h = Ah + (long)(m0+rowl   )*1024 + c4s;
  const unsigned short* pA1h = Ah + (long)(m0+rowl+64)*1024 + c4s;
  const unsigned short* pA0l = Al + (long)(m0+rowl   )*1024 + c4s;
  const unsigned short* pA1l = Al + (long)(m0+rowl+64)*1024 + c4s;
  const unsigned short* pB0h = Bh + (long)(n0+rowl   )*1024 + c4s;
  const unsigned short* pB1h = Bh + (long)(n0+rowl+64)*1024 + c4s;
  const unsigned short* pB0l = Bl + (long)(n0+rowl   )*1024 + c4s;
  const unsigned short* pB1l = Bl + (long)(n0+rowl+64)*1024 + c4s;
  int fc = (((((qm&1)<<2)|quad) ^ (qm>>1))<<3);

  floatx4 acc[4][4];
  #pragma unroll
  for(int m=0;m<4;m++)
    #pragma unroll
    for(int n=0;n<4;n++) acc[m][n] = (floatx4){0.f,0.f,0.f,0.f};

  for(int k0=0;k0<1024;k0+=32){
    __syncthreads();
    glds16(pA0h+k0, Ash+sdst); glds16(pA1h+k0, Ash+sdst+2048);
    glds16(pA0l+k0, Asl+sdst); glds16(pA1l+k0, Asl+sdst+2048);
    glds16(pB0h+k0, Bsh+sdst); glds16(pB1h+k0, Bsh+sdst+2048);
    glds16(pB0l+k0, Bsl+sdst); glds16(pB1l+k0, Bsl+sdst+2048);
    __syncthreads();
    short8 ah[4], al[4], bh[4], bl[4];
    #pragma unroll
    for(int m=0;m<4;m++){
      int ar = (wr*32 + m*8 + (qm>>1))*64 + fc;
      ah[m] = *(const short8*)(Ash+ar);
      al[m] = *(const short8*)(Asl+ar);
    }
    #pragma unroll
    for(int n=0;n<4;n++){
      int br = (wc*32 + n*8 + (qm>>1))*64 + fc;
      bh[n] = *(const short8*)(Bsh+br);
      bl[n] = *(const short8*)(Bsl+br);
    }
    #pragma unroll
    for(int m=0;m<4;m++)
      #pragma unroll
      for(int n=0;n<4;n++){
        acc[m][n] = __builtin_amdgcn_mfma_f32_16x16x32_bf16(ah[m],bh[n],acc[m][n],0,0,0);
        acc[m][n] = __builtin_amdgcn_mfma_f32_16x16x32_bf16(ah[m],bl[n],acc[m][n],0,0,0);
        acc[m][n] = __builtin_amdgcn_mfma_f32_16x16x32_bf16(al[m],bh[n],acc[m][n],0,0,0);
      }
  }
  #pragma unroll
  for(int m=0;m<4;m++){
    int row = m0 + wr*64 + m*16 + quad*4;
    #pragma unroll
    for(int r=0;r<4;r++){
      long rb = (long)(row+r)*1024 + n0 + wc*64;
      #pragma unroll
      for(int n=0;n<4;n++)
        Cf[rb+n*16+qm] = acc[m][n][r];
    }
  }
}

// ---- gate: softmax(h1 @ w_gate) (h1 split, wg fp32) ------------------------
__global__ __launch_bounds__(256) void k_gate(
    const unsigned short* __restrict__ hh, const unsigned short* __restrict__ hl,
    const float* __restrict__ wg, float* __restrict__ gates){
  int token = blockIdx.x*4 + (threadIdx.x>>6);
  int lane = threadIdx.x&63;
  long hb = (long)token*DMODEL + lane*16;
  const float* w = wg + lane*16*2;
  float s0=0.f, s1=0.f;
  for(int i=0;i<16;i++){
    float hv = bf2f(hh[hb+i]) + bf2f(hl[hb+i]);
    s0 += hv*w[2*i]; s1 += hv*w[2*i+1];
  }
  for(int off=32;off;off>>=1){ s0+=__shfl_down(s0,off,64); s1+=__shfl_down(s1,off,64); }
  if(lane==0){
    float m=fmaxf(s0,s1), e0=__expf(s0-m), e1=__expf(s1-m), inv=1.f/(e0+e1);
    gates[token*2]=e0*inv; gates[token*2+1]=e1*inv;
  }
}

// ---- flash attention v3: K/V staged in LDS (XOR-swizzled), shared by waves -
__global__ __launch_bounds__(256) void k_attn_flash3(
    const unsigned short* __restrict__ qh, const unsigned short* __restrict__ qlp,
    const unsigned short* __restrict__ vth, const unsigned short* __restrict__ vtl,
    const unsigned long long* __restrict__ mp, unsigned short* __restrict__ dmh,
    unsigned short* __restrict__ dml){
  __shared__ unsigned short Ksh[64*64], Ksl[64*64];     // 16KB
  __shared__ unsigned short Vsh[64*64], Vsl[64*64];     // 16KB
  __shared__ unsigned short PWh[4*16*64], PWl[4*16*64]; // 16KB (swizzled)
  int bh = blockIdx.y, b = bh>>4, h = bh&15;
  int tid = threadIdx.x, w = tid>>6, lane = tid&63;
  int qm = lane&15, quad = (lane>>4)&3;
  int q0 = blockIdx.x*64 + w*16;
  long qrow = (long)(b*SEQ+q0+qm)*6144 + h*DK;
  short8 a_qh0 = *(const short8*)(qh +qrow+quad*8);
  short8 a_qh1 = *(const short8*)(qh +qrow+32+quad*8);
  short8 a_ql0 = *(const short8*)(qlp+qrow+quad*8);
  short8 a_ql1 = *(const short8*)(qlp+qrow+32+quad*8);
  float m[4], l[4];
  floatx4 o0={0,0,0,0}, o1={0,0,0,0}, o2={0,0,0,0}, o3={0,0,0,0};
  #pragma unroll
  for(int r=0;r<4;r++){ m[r]=-3.0e38f; l[r]=0.f; }
  const unsigned long long* mrow = mp + ((long)b*SEQ + q0 + quad*4)*16;

  int r8 = lane>>3;                 // row within 8-row stripe
  int c8 = (lane&7) ^ r8;           // inverse-swizzled global chunk
  int d0 = w*512 + lane*8;          // LDS dest (shorts), linear per lane
  const unsigned short* pKh0 = qh  + (long)(b*SEQ + w*8 + r8)*6144 + 1024 + h*DK + c8*8;
  const unsigned short* pKl0 = qlp + (long)(b*SEQ + w*8 + r8)*6144 + 1024 + h*DK + c8*8;
  const unsigned short* pKh1 = pKh0 + 32L*6144;
  const unsigned short* pKl1 = pKl0 + 32L*6144;
  const unsigned short* pVh0 = vth + ((long)bh*DK + w*8 + r8)*SEQ + c8*8;
  const unsigned short* pVl0 = vtl + ((long)bh*DK + w*8 + r8)*SEQ + c8*8;
  const unsigned short* pVh1 = pVh0 + 32L*SEQ;
  const unsigned short* pVl1 = pVl0 + 32L*SEQ;
  int q7 = qm&7;

  for(int kt=0; kt<SEQ; kt+=64){
    __syncthreads();
    long ko = (long)kt*6144;
    glds16(pKh0+ko, Ksh+d0); glds16(pKh1+ko, Ksh+d0+2048);
    glds16(pKl0+ko, Ksl+d0); glds16(pKl1+ko, Ksl+d0+2048);
    glds16(pVh0+kt, Vsh+d0); glds16(pVh1+kt, Vsh+d0+2048);
    glds16(pVl0+kt, Vsl+d0); glds16(pVl1+kt, Vsl+d0+2048);
    __syncthreads();

    int wd = kt>>6;
    unsigned long long mws[4] = {mrow[wd], mrow[16+wd], mrow[32+wd], mrow[48+wd]};
    floatx4 s[4];
    #pragma unroll
    for(int st=0;st<4;st++){
      int krow = (st*16+qm)*64;
      short8 kh0 = *(const short8*)(Ksh + krow + ((quad    ^q7)<<3));
      short8 kh1 = *(const short8*)(Ksh + krow + (((4|quad)^q7)<<3));
      short8 kl0 = *(const short8*)(Ksl + krow + ((quad    ^q7)<<3));
      short8 kl1 = *(const short8*)(Ksl + krow + (((4|quad)^q7)<<3));
      floatx4 acc = {0,0,0,0};
      acc = __builtin_amdgcn_mfma_f32_16x16x32_bf16(a_qh0,kh0,acc,0,0,0);
      acc = __builtin_amdgcn_mfma_f32_16x16x32_bf16(a_qh1,kh1,acc,0,0,0);
      acc = __builtin_amdgcn_mfma_f32_16x16x32_bf16(a_qh0,kl0,acc,0,0,0);
      acc = __builtin_amdgcn_mfma_f32_16x16x32_bf16(a_qh1,kl1,acc,0,0,0);
      acc = __builtin_amdgcn_mfma_f32_16x16x32_bf16(a_ql0,kh0,acc,0,0,0);
      acc = __builtin_amdgcn_mfma_f32_16x16x32_bf16(a_ql1,kh1,acc,0,0,0);
      s[st] = acc;
    }
    #pragma unroll
    for(int r=0;r<4;r++){
      float v0 = ((mws[r]>>(   qm))&1) ? s[0][r]*0.125f : -1e9f;
      float v1 = ((mws[r]>>(16+qm))&1) ? s[1][r]*0.125f : -1e9f;
      float v2 = ((mws[r]>>(32+qm))&1) ? s[2][r]*0.125f : -1e9f;
      float v3 = ((mws[r]>>(48+qm))&1) ? s[3][r]*0.125f : -1e9f;
      float tm = fmaxf(fmaxf(v0,v1), fmaxf(v2,v3));
      tm = fmaxf(tm, __shfl_xor(tm,1,16));
      tm = fmaxf(tm, __shfl_xor(tm,2,16));
      tm = fmaxf(tm, __shfl_xor(tm,4,16));
      tm = fmaxf(tm, __shfl_xor(tm,8,16));
      float nm = fmaxf(m[r], tm);
      float al = __expf(m[r]-nm);
      m[r] = nm;
      float p0=__expf(v0-nm), p1=__expf(v1-nm), p2=__expf(v2-nm), p3=__expf(v3-nm);
      float rs = p0+p1+p2+p3;
      rs += __shfl_xor(rs,1,16); rs += __shfl_xor(rs,2,16);
      rs += __shfl_xor(rs,4,16); rs += __shfl_xor(rs,8,16);
      l[r] = l[r]*al + rs;
      o0[r]*=al; o1[r]*=al; o2[r]*=al; o3[r]*=al;
      int row = quad*4+r, rsw = row&7;
      int pb = w*1024 + row*64 + (qm&7);
      unsigned short hi,lo;
      splitbf(p0,hi,lo); PWh[pb + ((( (qm>>3))^rsw)<<3)]=hi; PWl[pb + ((( (qm>>3))^rsw)<<3)]=lo;
      splitbf(p1,hi,lo); PWh[pb + (((2|(qm>>3))^rsw)<<3)]=hi; PWl[pb + (((2|(qm>>3))^rsw)<<3)]=lo;
      splitbf(p2,hi,lo); PWh[pb + (((4|(qm>>3))^rsw)<<3)]=hi; PWl[pb + (((4|(qm>>3))^rsw)<<3)]=lo;
      splitbf(p3,hi,lo); PWh[pb + (((6|(qm>>3))^rsw)<<3)]=hi; PWl[pb + (((6|(qm>>3))^rsw)<<3)]=lo;
    }
    __builtin_amdgcn_wave_barrier();
    int prb = w*1024 + qm*64;
    short8 ph0 = *(const short8*)(PWh + prb + ((quad    ^q7)<<3));
    short8 ph1 = *(const short8*)(PWh + prb + (((4|quad)^q7)<<3));
    short8 pl0 = *(const short8*)(PWl + prb + ((quad    ^q7)<<3));
    short8 pl1 = *(const short8*)(PWl + prb + (((4|quad)^q7)<<3));
    __builtin_amdgcn_wave_barrier();
    {
      int c0 = (quad    ^q7)<<3;
      int c1 = ((4|quad)^q7)<<3;
      int vr0 = (0*16+qm)*64, vr1 = (1*16+qm)*64, vr2 = (2*16+qm)*64, vr3 = (3*16+qm)*64;
      short8 v0h0=*(const short8*)(Vsh+vr0+c0), v0h1=*(const short8*)(Vsh+vr0+c1);
      short8 v1h0=*(const short8*)(Vsh+vr1+c0), v1h1=*(const short8*)(Vsh+vr1+c1);
      short8 v2h0=*(const short8*)(Vsh+vr2+c0), v2h1=*(const short8*)(Vsh+vr2+c1);
      short8 v3h0=*(const short8*)(Vsh+vr3+c0), v3h1=*(const short8*)(Vsh+vr3+c1);
      short8 v0l0=*(const short8*)(Vsl+vr0+c0), v0l1=*(const short8*)(Vsl+vr0+c1);
      short8 v1l0=*(const short8*)(Vsl+vr1+c0), v1l1=*(const short8*)(Vsl+vr1+c1);
      short8 v2l0=*(const short8*)(Vsl+vr2+c0), v2l1=*(const short8*)(Vsl+vr2+c1);
      short8 v3l0=*(const short8*)(Vsl+vr3+c0), v3l1=*(const short8*)(Vsl+vr3+c1);
      o0 = __builtin_amdgcn_mfma_f32_16x16x32_bf16(ph0,v0h0,o0,0,0,0);
      o0 = __builtin_amdgcn_mfma_f32_16x16x32_bf16(ph1,v0h1,o0,0,0,0);
      o0 = __builtin_amdgcn_mfma_f32_16x16x32_bf16(ph0,v0l0,o0,0,0,0);
      o0 = __builtin_amdgcn_mfma_f32_16x16x32_bf16(ph1,v0l1,o0,0,0,0);
      o0 = __builtin_amdgcn_mfma_f32_16x16x32_bf16(pl0,v0h0,o0,0,0,0);
      o0 = __builtin_amdgcn_mfma_f32_16x16x32_bf16(pl1,v0h1,o0,0,0,0);
      o1 = __builtin_amdgcn_mfma_f32_16x16x32_bf16(ph0,v1h0,o1,0,0,0);
      o1 = __builtin_amdgcn_mfma_f32_16x16x32_bf16(ph1,v1h1,o1,0,0,0);
      o1 = __builtin_amdgcn_mfma_f32_16x16x32_bf16(ph0,v1l0,o1,0,0,0);
      o1 = __builtin_amdgcn_mfma_f32_16x16x32_bf16(ph1,v1l1,o1,0,0,0);
      o1 = __builtin_amdgcn_mfma_f32_16x16x32_bf16(pl0,v1h0,o1,0,0,0);
      o1 = __builtin_amdgcn_mfma_f32_16x16x32_bf16(pl1,v1h1,o1,0,0,0);
      o2 = __builtin_amdgcn_mfma_f32_16x16x32_bf16(ph0,v2h0,o2,0,0,0);
      o2 = __builtin_amdgcn_mfma_f32_16x16x32_bf16(ph1,v2h1,o2,0,0,0);
      o2 = __builtin_amdgcn_mfma_f32_16x16x32_bf16(ph0,v2l0,o2,0,0,0);
      o2 = __builtin_amdgcn_mfma_f32_16x16x32_bf16(ph1,v2l1,o2,0,0,0);
      o2 = __builtin_amdgcn_mfma_f32_16x16x32_bf16(pl0,v2h0,o2,0,0,0);
      o2 = __builtin_amdgcn_mfma_f32_16x16x32_bf16(pl1,v2h1,o2,0,0,0);
      o3 = __builtin_amdgcn_mfma_f32_16x16x32_bf16(ph0,v3h0,o3,0,0,0);
      o3 = __builtin_amdgcn_mfma_f32_16x16x32_bf16(ph1,v3h1,o3,0,0,0);
      o3 = __builtin_amdgcn_mfma_f32_16x16x32_bf16(ph0,v3l0,o3,0,0,0);
      o3 = __builtin_amdgcn_mfma_f32_16x16x32_bf16(ph1,v3l1,o3,0,0,0);
      o3 = __builtin_amdgcn_mfma_f32_16x16x32_bf16(pl0,v3h0,o3,0,0,0);
      o3 = __builtin_amdgcn_mfma_f32_16x16x32_bf16(pl1,v3h1,o3,0,0,0);
    }
  }
  #pragma unroll
  for(int r=0;r<4;r++){
    float inv = 1.f/l[r];
    long rb = ((long)(b*SEQ + q0 + quad*4 + r))*DMODEL + h*DK;
    unsigned short hi,lo;
    splitbf(o0[r]*inv,hi,lo); dmh[rb+   qm]=hi; dml[rb+   qm]=lo;
    splitbf(o1[r]*inv,hi,lo); dmh[rb+16+qm]=hi; dml[rb+16+qm]=lo;
    splitbf(o2[r]*inv,hi,lo); dmh[rb+32+qm]=hi; dml[rb+32+qm]=lo;
    splitbf(o3[r]*inv,hi,lo); dmh[rb+48+qm]=hi; dml[rb+48+qm]=lo;
  }
}

// ---- delta ctx via MFMA + fused ksum ---------------------------------------
// ctx[bh] = kdT[bh] @ vdT[bh]^T over s (K=1024); ksum[bh][d] = sum_s relu(kd).
// kdT/vdT layout [bh][dk=64][s=1024] split planes. One block per bh, 4 waves.
__global__ __launch_bounds__(256) void k_delta_ctx2(
    const unsigned short* __restrict__ kdTh, const unsigned short* __restrict__ kdTl,
    const unsigned short* __restrict__ vdTh, const unsigned short* __restrict__ vdTl,
    float* __restrict__ ctx, float* __restrict__ ksum){
  int bh = blockIdx.x;
  int tid = threadIdx.x, w = tid>>6, lane = tid&63;
  int qm = lane&15, quad = lane>>4;
  long abase = ((long)bh*DK + w*16 + qm)*SEQ + quad*8;
  long bbase = ((long)bh*DK + qm)*SEQ + quad*8;
  floatx4 acc[4];
  #pragma unroll
  for(int n=0;n<4;n++) acc[n] = (floatx4){0.f,0.f,0.f,0.f};
  float ks = 0.f;
  #pragma unroll 2
  for(int s0=0;s0<SEQ;s0+=32){
    short8 ah = *(const short8*)(kdTh + abase + s0);
    short8 al = *(const short8*)(kdTl + abase + s0);
    #pragma unroll
    for(int j=0;j<8;j++)
      ks += fmaxf(bf2f((unsigned short)ah[j]) + bf2f((unsigned short)al[j]), 0.f);
    #pragma unroll
    for(int n=0;n<4;n++){
      short8 bh8 = *(const short8*)(vdTh + bbase + (long)n*16*SEQ + s0);
      short8 bl8 = *(const short8*)(vdTl + bbase + (long)n*16*SEQ + s0);
      acc[n] = __builtin_amdgcn_mfma_f32_16x16x32_bf16(ah,bh8,acc[n],0,0,0);
      acc[n] = __builtin_amdgcn_mfma_f32_16x16x32_bf16(ah,bl8,acc[n],0,0,0);
      acc[n] = __builtin_amdgcn_mfma_f32_16x16x32_bf16(al,bh8,acc[n],0,0,0);
    }
  }
  long cb = (long)bh*DK*DK;
  #pragma unroll
  for(int n=0;n<4;n++)
    #pragma unroll
    for(int r=0;r<4;r++)
      ctx[cb + (long)(w*16 + quad*4 + r)*DK + n*16 + qm] = acc[n][r];
  // ksum: lane (w,quad,qm) holds partial over s≡quad*8..quad*8+7 (mod 32);
  // reduce across quad (lane^16, lane^32), write from quad==0.
  ks += __shfl_xor(ks,16,64);
  ks += __shfl_xor(ks,32,64);
  if(quad==0) ksum[bh*DK + w*16 + qm] = ks;
}

// ---- delta: out = relu(qd)@ctx / z, split-bf16 output ----------------------
__global__ __launch_bounds__(256) void k_delta_out(
    const unsigned short* __restrict__ qh, const unsigned short* __restrict__ qlp,
    const float* __restrict__ ctx, const float* __restrict__ ksum,
    unsigned short* __restrict__ dlh, unsigned short* __restrict__ dll){
  int tok = blockIdx.x, b = tok>>10;
  int tid = threadIdx.x;
  __shared__ float ql[DMODEL];
  long sb = (long)tok*6144 + 3072;
  for(int c=tid;c<DMODEL;c+=256)
    ql[c] = fmaxf(bf2f(qh[sb+c]) + bf2f(qlp[sb+c]), 0.f);
  __syncthreads();
  int h = tid>>4, dg = (tid&15)*4;
  int bh = b*NHEAD + h;
  const float* C = ctx + (long)bh*DK*DK;
  const float* KS = ksum + bh*DK;
  float a0=0,a1=0,a2=0,a3=0,z=0;
  for(int d=0;d<DK;d++){
    float q = ql[h*DK + d];
    z += q * KS[d];
    const float* cr = C + d*DK + dg;
    a0 += q*cr[0]; a1 += q*cr[1]; a2 += q*cr[2]; a3 += q*cr[3];
  }
  float inv = 1.f/(z + 1e-6f);
  long db = (long)tok*DMODEL + h*DK + dg;
  unsigned short hi,lo;
  splitbf(a0*inv,hi,lo); dlh[db  ]=hi; dll[db  ]=lo;
  splitbf(a1*inv,hi,lo); dlh[db+1]=hi; dll[db+1]=lo;
  splitbf(a2*inv,hi,lo); dlh[db+2]=hi; dll[db+2]=lo;
  splitbf(a3*inv,hi,lo); dlh[db+3]=hi; dll[db+3]=lo;
}

// ---- fused: x1 = x+g0*dp+g1*dlp (fp32); h2=LN2(x1); router top2 ------------
__global__ __launch_bounds__(256) void k_comb_router(
    const float* __restrict__ x, const float* __restrict__ dp,
    const float* __restrict__ dlp, const float* __restrict__ gates,
    const float* __restrict__ g, const float* __restrict__ bb,
    const float* __restrict__ wr, unsigned short* __restrict__ h2b,
    float* __restrict__ topw, int* __restrict__ topi, int* __restrict__ counts){
  __shared__ float red[4];
  __shared__ float ered[4][8];
  int t = blockIdx.x, tid = threadIdx.x;
  float g0 = gates[t*2], g1 = gates[t*2+1];
  long base = (long)t*DMODEL + tid*4;
  floatx4 xv = *(const floatx4*)(x + base);
  float v[4];
  for(int i=0;i<4;i++) v[i] = xv[i] + g0*dp[base+i] + g1*dlp[base+i];
  float s = block_sum(v[0]+v[1]+v[2]+v[3], red);
  float mu = s*(1.f/DMODEL);
  float q=0.f; for(int i=0;i<4;i++){ float d=v[i]-mu; q+=d*d; }
  q = block_sum(q, red);
  float inv = rsqrtf(q*(1.f/DMODEL)+1e-5f);
  float a[8]; for(int e=0;e<8;e++) a[e]=0.f;
  for(int i=0;i<4;i++){
    int d = tid*4+i;
    float hv = (v[i]-mu)*inv*g[d] + bb[d];
    h2b[base+i] = f2bf(hv);
    const float* wrow = wr + (long)d*NEXP;
    for(int e=0;e<8;e++) a[e] += hv*wrow[e];
  }
  for(int off=32;off;off>>=1)
    for(int e=0;e<8;e++) a[e] += __shfl_down(a[e],off,64);
  int w = tid>>6;
  if((tid&63)==0) for(int e=0;e<8;e++) ered[w][e]=a[e];
  __syncthreads();
  if(tid==0){
    float lg[8];
    for(int e=0;e<8;e++) lg[e]=ered[0][e]+ered[1][e]+ered[2][e]+ered[3][e];
    int i0=0; for(int e=1;e<8;e++) if(lg[e]>lg[i0]) i0=e;
    int i1=-1; for(int e=0;e<8;e++){ if(e==i0) continue; if(i1<0||lg[e]>lg[i1]) i1=e; }
    float mm=fmaxf(lg[i0],lg[i1]), e0=__expf(lg[i0]-mm), e1=__expf(lg[i1]-mm), s2=1.f/(e0+e1);
    topw[t*2]=e0*s2; topw[t*2+1]=e1*s2;
    topi[t*2]=i0; topi[t*2+1]=i1;
    atomicAdd(&counts[i0],1); atomicAdd(&counts[i1],1);
  }
}

// ---- expert segment offsets + tile table (128-row tiles) -------------------
__global__ void k_meta(const int* __restrict__ counts, int* offs, int* tE,
                       int* tR0, int* tR1, int* ntp, int* cursor){
  if(threadIdx.x==0){
    int o=0, nt=0;
    for(int e=0;e<NEXP;e++){
      offs[e]=o; cursor[e]=0;
      int n=counts[e];
      for(int t=0;t<(n+127)/128;t++){ tE[nt]=e; tR0[nt]=o+t*128; tR1[nt]=o+n; nt++; }
      o+=n;
    }
    offs[NEXP]=o; ntp[0]=nt;
  }
}

// ---- scatter tokens into expert-sorted slots -------------------------------
__global__ __launch_bounds__(256) void k_scatter(
    const int* __restrict__ topi, const int* __restrict__ offs,
    int* cursor, int* perm, int* slotof){
  int token = blockIdx.x*256 + threadIdx.x;
  for(int k=0;k<2;k++){
    int e = topi[token*2+k];
    int pos = atomicAdd(&cursor[e],1);
    int slot = offs[e]+pos;
    perm[slot]=token; slotof[token*2+k]=slot;
  }
}

// ---- MoE GEMM, m97 structure + superrow XOR swizzle (128x128, 3 blk/CU) ----
template<int GELU, int GATHER>
__global__ __launch_bounds__(256) void k_moe128(
    const unsigned short* __restrict__ A, const unsigned short* __restrict__ BtA,
    unsigned short* __restrict__ C, const int* __restrict__ perm,
    const int* __restrict__ ntp, const int* __restrict__ tE,
    const int* __restrict__ tR0, const int* __restrict__ tR1,
    int K, int N){
  int bz = blockIdx.y;
  if(bz >= ntp[0]) return;
  int e = tE[bz], r0t = tR0[bz], r1t = tR1[bz];
  __shared__ unsigned short As[128*32], Bs[128*32];
  int tid = threadIdx.x, w = tid>>6, lane = tid&63;
  int qm = lane&15, quad = lane>>4;
  int wr = w>>1, wc = w&1;
  int n0 = blockIdx.x*128;
  int lg = lane>>3, pp = lane&7, px = pp ^ lg;
  int rowl = (w<<4) + (lg<<1) + (px>>2);
  int c4s = (px&3)*8;
  int sdst = w*512 + lane*8;
  int fc = (((((qm&1)<<2)|quad) ^ (qm>>1))<<3);
  int gr0 = r0t + rowl, gr1 = gr0 + 64;
  int gc0 = gr0 < 8191 ? gr0 : 8191;
  int gc1 = gr1 < 8191 ? gr1 : 8191;
  const unsigned short *pA0, *pA1;
  if(GATHER){
    pA0 = A + (long)perm[gc0]*K + c4s;
    pA1 = A + (long)perm[gc1]*K + c4s;
  }else{
    pA0 = A + (long)gc0*K + c4s;
    pA1 = A + (long)gc1*K + c4s;
  }
  const unsigned short* Bt = BtA + (long)e*N*K;
  const unsigned short* pB0 = Bt + (long)(n0+rowl   )*K + c4s;
  const unsigned short* pB1 = Bt + (long)(n0+rowl+64)*K + c4s;

  floatx4 acc[4][4];
  #pragma unroll
  for(int m=0;m<4;m++)
    #pragma unroll
    for(int n=0;n<4;n++) acc[m][n] = (floatx4){0.f,0.f,0.f,0.f};

  for(int k0=0;k0<K;k0+=32){
    __syncthreads();
    glds16(pA0+k0, As+sdst); glds16(pA1+k0, As+sdst+2048);
    glds16(pB0+k0, Bs+sdst); glds16(pB1+k0, Bs+sdst+2048);
    __syncthreads();
    short8 af[4], bf[4];
    #pragma unroll
    for(int m=0;m<4;m++)
      af[m] = *(const short8*)(As + (wr*32 + m*8 + (qm>>1))*64 + fc);
    #pragma unroll
    for(int n=0;n<4;n++)
      bf[n] = *(const short8*)(Bs + (wc*32 + n*8 + (qm>>1))*64 + fc);
    #pragma unroll
    for(int m=0;m<4;m++)
      #pragma unroll
      for(int n=0;n<4;n++)
        acc[m][n] = __builtin_amdgcn_mfma_f32_16x16x32_bf16(af[m],bf[n],acc[m][n],0,0,0);
  }
  #pragma unroll
  for(int m=0;m<4;m++){
    int row = r0t + wr*64 + m*16 + quad*4;
    #pragma unroll
    for(int r=0;r<4;r++){
      if(row+r < r1t){
        long rb = (long)(row+r)*N + n0 + wc*64;
        #pragma unroll
        for(int n=0;n<4;n++){
          float xx = acc[m][n][r];
          if(GELU) xx = 0.5f*xx*(1.f+erff(xx*0.70710678f));
          C[rb+n*16+qm] = f2bf(xx);
        }
      }
    }
  }
}

// ---- final: out = x + g0*dp + g1*dlp + w0*Y[s0] + w1*Y[s1] (fp32) ----------
__global__ __launch_bounds__(256) void k_final(
    const float* __restrict__ x, const float* __restrict__ dp,
    const float* __restrict__ dlp, const float* __restrict__ gates,
    const unsigned short* __restrict__ Y, const int* __restrict__ slotof,
    const float* __restrict__ topw, float* __restrict__ out){
  int t = blockIdx.x, tid = threadIdx.x;
  int s0 = slotof[t*2], s1 = slotof[t*2+1];
  float w0 = topw[t*2], w1 = topw[t*2+1];
  float g0 = gates[t*2], g1 = gates[t*2+1];
  long base = (long)t*DMODEL + tid*4;
  const unsigned short* y0 = Y + (long)s0*DMODEL + tid*4;
  const unsigned short* y1 = Y + (long)s1*DMODEL + tid*4;
  floatx4 xv = *(const floatx4*)(x + base);
  for(int i=0;i<4;i++)
    out[base+i] = xv[i] + g0*dp[base+i] + g1*dlp[base+i]
                        + w0*bf2f(y0[i]) + w1*bf2f(y1[i]);
}

// ===========================================================================
extern "C" void kernel_launch(void* const* d_in, const int* in_sizes, int n_in,
                              void* d_out, int out_size, void* d_ws, size_t ws_size,
                              hipStream_t stream){
  const float* x    = (const float*)d_in[0];
  const int*   mask = (const int*)d_in[1];
  const float* ln1g = (const float*)d_in[2];
  const float* ln1b = (const float*)d_in[3];
  const float* wq   = (const float*)d_in[4];
  const float* wk   = (const float*)d_in[5];
  const float* wv   = (const float*)d_in[6];
  const float* wo   = (const float*)d_in[7];
  const float* wqd  = (const float*)d_in[8];
  const float* wkd  = (const float*)d_in[9];
  const float* wvd  = (const float*)d_in[10];
  const float* wod  = (const float*)d_in[11];
  const float* wg   = (const float*)d_in[12];
  const float* ln2g = (const float*)d_in[13];
  const float* ln2b = (const float*)d_in[14];
  const float* wr   = (const float*)d_in[15];
  const float* ew1  = (const float*)d_in[16];
  const float* ew2  = (const float*)d_in[17];
  float* out = (float*)d_out;

  char* p = (char*)d_ws;
  auto alloc = [&](size_t b)->char*{ char* r=p; p += (b + 255) & ~(size_t)255; return r; };
  unsigned short* WtAllh = (unsigned short*)alloc(6144L*1024*2);
  unsigned short* WtAlll = (unsigned short*)alloc(6144L*1024*2);
  unsigned short* WoTh   = (unsigned short*)alloc(1024L*1024*2);
  unsigned short* WoTl   = (unsigned short*)alloc(1024L*1024*2);
  unsigned short* WodTh  = (unsigned short*)alloc(1024L*1024*2);
  unsigned short* WodTl  = (unsigned short*)alloc(1024L*1024*2);
  unsigned short* eW1T   = (unsigned short*)alloc(8L*2048*1024*2);
  unsigned short* eW2T   = (unsigned short*)alloc(8L*1024*2048*2);
  unsigned short* h1h    = (unsigned short*)alloc(4096L*1024*2);  // later vTh
  unsigned short* h1l    = (unsigned short*)alloc(4096L*1024*2);  // later vTl
  unsigned short* qkvh   = (unsigned short*)alloc(4096L*6144*2);  // later dproj+dlproj (fp32)
  unsigned short* qkvl   = (unsigned short*)alloc(4096L*6144*2);  // later H
  unsigned short* dmh    = (unsigned short*)alloc(4096L*1024*2);  // first vdTh, then attn out, then Y
  unsigned short* dml    = (unsigned short*)alloc(4096L*1024*2);  // first vdTl
  unsigned short* dlh    = (unsigned short*)alloc(4096L*1024*2);  // first kdTh
  unsigned short* dll    = (unsigned short*)alloc(4096L*1024*2);  // first kdTl
  float* ctx   = (float*)alloc(64L*64*64*4);
  float* ksum  = (float*)alloc(64L*64*4);
  float* gates = (float*)alloc(4096L*2*4);
  unsigned short* h2b = (unsigned short*)alloc(4096L*1024*2);
  float* topw = (float*)alloc(4096L*2*4);
  int* topi   = (int*)alloc(4096L*2*4);
  int* slotof = (int*)alloc(4096L*2*4);
  int* perm   = (int*)alloc(8192L*4);
  int* counts = (int*)alloc(64*4);
  int* cursor = (int*)alloc(64*4);
  int* offs   = (int*)alloc(64*4);
  int* ntp    = (int*)alloc(64*4);
  int* tE     = (int*)alloc(MAXTILE*4);
  int* tR0    = (int*)alloc(MAXTILE*4);
  int* tR1    = (int*)alloc(MAXTILE*4);
  unsigned long long* mpack = (unsigned long long*)alloc(4L*1024*16*8);
  if ((size_t)(p - (char*)d_ws) > ws_size) return;  // ws too small -> absmax==ref max

  unsigned short* vTh = h1h;                    // after h1 consumed (qkv gemm + gate)
  unsigned short* vTl = h1l;
  unsigned short* kdTh = dlh;                   // until delta_out overwrites
  unsigned short* kdTl = dll;
  unsigned short* vdTh = dmh;                   // consumed by ctx2 BEFORE attn writes dmh
  unsigned short* vdTl = dml;
  float* dproj  = (float*)qkvh;                 // after qkv consumed (attn+delta)
  float* dlproj = (float*)(qkvh + 8388608);     // second 16.8MB of qkvh region
  unsigned short* H = qkvl;                     // after qkv consumed
  unsigned short* Y = dmh;                      // spans dmh+dml (16.8MB), after projections read dm

  dim3 tb(256);
  // mask bit-pack (independent)
  k_maskpack<<<16384,tb,0,stream>>>(mask, mpack);
  // weight transposes: attention weights split, MoE weights single bf16
  k_transpose_f2<<<dim3(32,32,1),tb,0,stream>>>(wq,  WtAllh+0L*1048576, WtAlll+0L*1048576, 1024,1024, 0,0);
  k_transpose_f2<<<dim3(32,32,1),tb,0,stream>>>(wk,  WtAllh+1L*1048576, WtAlll+1L*1048576, 1024,1024, 0,0);
  k_transpose_f2<<<dim3(32,32,1),tb,0,stream>>>(wv,  WtAllh+2L*1048576, WtAlll+2L*1048576, 1024,1024, 0,0);
  k_transpose_f2<<<dim3(32,32,1),tb,0,stream>>>(wqd, WtAllh+3L*1048576, WtAlll+3L*1048576, 1024,1024, 0,0);
  k_transpose_f2<<<dim3(32,32,1),tb,0,stream>>>(wkd, WtAllh+4L*1048576, WtAlll+4L*1048576, 1024,1024, 0,0);
  k_transpose_f2<<<dim3(32,32,1),tb,0,stream>>>(wvd, WtAllh+5L*1048576, WtAlll+5L*1048576, 1024,1024, 0,0);
  k_transpose_f2<<<dim3(32,32,1),tb,0,stream>>>(wo,  WoTh,  WoTl,  1024,1024, 0,0);
  k_transpose_f2<<<dim3(32,32,1),tb,0,stream>>>(wod, WodTh, WodTl, 1024,1024, 0,0);
  k_transpose_f<<<dim3(64,32,8),tb,0,stream>>>(ew1, eW1T, 2048,1024, 1024L*2048, 2048L*1024);
  k_transpose_f<<<dim3(32,64,8),tb,0,stream>>>(ew2, eW2T, 1024,2048, 2048L*1024, 1024L*2048);
  // LN1 -> h1 split
  k_ln1<<<4096,tb,0,stream>>>(x, ln1g, ln1b, h1h, h1l);
  // qkv: all 6 projections, split in/out. grid 48x32 tiles of 128, linear+swz.
  k_gemm128_ss<1><<<dim3(1536),tb,0,stream>>>(h1h,h1l, WtAllh,WtAlll, qkvh,qkvl,nullptr,
                                              1024, 1024, 1024, 6144, 48);
  // gate (fp32 path)
  k_gate<<<1024,tb,0,stream>>>(h1h, h1l, wg, gates);
  // transposed slices: v (attn), kd, vd (delta; vd aliases dmh/dml) — fused
  k_vt3<<<dim3(32,6,64),tb,0,stream>>>(qkvh, qkvl, vTh, vTl, kdTh, kdTl, vdTh, vdTl);
  // delta ctx (+fused ksum) FIRST (consume vdT before attention overwrites dmh/dml)
  k_delta_ctx2<<<64,tb,0,stream>>>(kdTh, kdTl, vdTh, vdTl, ctx, ksum);
  // flash attention v3 (split precision, LDS-staged K/V) -> dmh/dml
  k_attn_flash3<<<dim3(16,64),tb,0,stream>>>(qkvh, qkvl, vTh, vTl, mpack, dmh, dml);
  // delta out (overwrites kdT buffers dlh/dll)
  k_delta_out<<<4096,tb,0,stream>>>(qkvh, qkvl, ctx, ksum, dlh, dll);
  // merged output projections -> fp32 (512 blocks = 2/CU)
  k_proj2<<<dim3(512),tb,0,stream>>>(dmh,dml, dlh,dll, WoTh,WoTl, WodTh,WodTl,
                                     dproj, dlproj);
  // residual + gate-mix + LN2 + router (all fp32)
  hipMemsetAsync(counts, 0, NEXP*sizeof(int), stream);
  k_comb_router<<<4096,tb,0,stream>>>(x, dproj, dlproj, gates, ln2g, ln2b, wr,
                                      h2b, topw, topi, counts);
  k_meta<<<1,64,0,stream>>>(counts, offs, tE, tR0, tR1, ntp, cursor);
  k_scatter<<<16,tb,0,stream>>>(topi, offs, cursor, perm, slotof);
  // expert GEMMs (128x128 tiles: 152 regs/wave -> 3 blocks/CU latency hiding)
  k_moe128<1,1><<<dim3(16,72),tb,0,stream>>>(h2b, eW1T, H, perm, ntp, tE, tR0, tR1,
                                             1024, 2048);
  k_moe128<0,0><<<dim3(8,72),tb,0,stream>>>(H, eW2T, Y, perm, ntp, tE, tR0, tR1,
                                            2048, 1024);
  // final residual combine
  k_final<<<4096,tb,0,stream>>>(x, dproj, dlproj, gates, Y, slotof, topw, out);
}

// Round 7
// 971.405 us; speedup vs baseline: 1.2691x; 1.0327x over previous
//
#include <hip/hip_runtime.h>
#include <stdint.h>

// ---------------------------------------------------------------------------
// Qwen3.5-style layer on MI355X. fp32 in/out. Pre-router chain computed in
// split-bf16 (hi/lo) 3-pass MFMA => ~fp32 precision so the discrete top-2
// expert selection matches the fp32 reference. MoE GEMMs single bf16.
// R5-R10: m97-structure GEMMs (global_load_lds w16, superrow XOR swizzle,
//     XCD swizzle), LDS-staged attention, MFMA delta-ctx, fused vt3/ksum,
//     merged proj2, moe at 128x128 (occupancy > density when latency-bound).
// R11: (a) qkv block remap: per-XCD chunk bx-major with 4-deep by minor
//     (concurrent L2 working set 25->14MB, B streamed 1x not 4x per chunk);
//     (b) proj2 BK=64 (64KB LDS, occupancy already 2/CU -> unchanged;
//     barriers halved); (c) moe128 BK=64 (32KB LDS, occupancy stays 3/CU;
//     32 MFMA per barrier-pair instead of 16). All bit-identical numerics.
// ---------------------------------------------------------------------------

typedef __attribute__((ext_vector_type(8))) short short8;   // 8 bf16 = 16B
typedef __attribute__((ext_vector_type(4))) float floatx4;

#define DMODEL 1024
#define SEQ    1024
#define NHEAD  16
#define DK     64
#define DFF    2048
#define NEXP   8
#define MAXTILE 144

__device__ __forceinline__ float bf2f(unsigned short h){
  union{unsigned u;float f;}v; v.u=((unsigned)h)<<16; return v.f;
}
__device__ __forceinline__ unsigned short f2bf(float f){
  union{float f;unsigned u;}v; v.f=f;
  unsigned r=(v.u + 0x7FFFu + ((v.u>>16)&1u))>>16; return (unsigned short)r;
}
__device__ __forceinline__ void splitbf(float v, unsigned short& hi, unsigned short& lo){
  hi = f2bf(v); lo = f2bf(v - bf2f(hi));
}

// async global->LDS, 16B per lane. LDS dest is wave-uniform base + lane*16.
__device__ __forceinline__ void glds16(const unsigned short* g, unsigned short* l){
  __builtin_amdgcn_global_load_lds(
      (const __attribute__((address_space(1))) void*)g,
      (__attribute__((address_space(3))) void*)l, 16, 0, 0);
}

__device__ __forceinline__ float block_sum(float v, float* red){
  for(int off=32;off;off>>=1) v += __shfl_down(v,off,64);
  int w = threadIdx.x>>6;
  __syncthreads();
  if((threadIdx.x&63)==0) red[w]=v;
  __syncthreads();
  return red[0]+red[1]+red[2]+red[3];
}

// ---- pack mask to bits: one wave per 64-int chunk --------------------------
__global__ __launch_bounds__(256) void k_maskpack(
    const int* __restrict__ mask, unsigned long long* __restrict__ mp){
  int gw = blockIdx.x*4 + (threadIdx.x>>6);
  int lane = threadIdx.x&63;
  unsigned long long bm = __ballot(mask[(long)gw*64 + lane] != 0);
  if(lane==0) mp[gw]=bm;
}

// ---- transpose fp32 -> split bf16 planes: dst[c][r] = src[r][c] ------------
__global__ __launch_bounds__(256) void k_transpose_f2(
    const float* __restrict__ src, unsigned short* __restrict__ dh,
    unsigned short* __restrict__ dl, long srs, long drs, long sbs, long dbs){
  __shared__ float t[32][33];
  src += (long)blockIdx.z*sbs; dh += (long)blockIdx.z*dbs; dl += (long)blockIdx.z*dbs;
  int c0 = blockIdx.x*32, r0 = blockIdx.y*32;
  int tx = threadIdx.x & 31, ty = threadIdx.x >> 5;
  for(int i=0;i<32;i+=8)
    t[ty+i][tx] = src[(long)(r0+ty+i)*srs + (c0+tx)];
  __syncthreads();
  for(int i=0;i<32;i+=8){
    unsigned short hi,lo; splitbf(t[tx][ty+i],hi,lo);
    long idx = (long)(c0+ty+i)*drs + (r0+tx);
    dh[idx]=hi; dl[idx]=lo;
  }
}

// ---- transpose fp32 -> single bf16 (MoE weights) ---------------------------
__global__ __launch_bounds__(256) void k_transpose_f(
    const float* __restrict__ src, unsigned short* __restrict__ dst,
    long srs, long drs, long sbs, long dbs){
  __shared__ float t[32][33];
  src += (long)blockIdx.z*sbs; dst += (long)blockIdx.z*dbs;
  int c0 = blockIdx.x*32, r0 = blockIdx.y*32;
  int tx = threadIdx.x & 31, ty = threadIdx.x >> 5;
  for(int i=0;i<32;i+=8)
    t[ty+i][tx] = src[(long)(r0+ty+i)*srs + (c0+tx)];
  __syncthreads();
  for(int i=0;i<32;i+=8)
    dst[(long)(c0+ty+i)*drs + (r0+tx)] = f2bf(t[tx][ty+i]);
}

// ---- vT3: 3 slices (v, kd, vd), both planes, all (b,h) in one launch -------
__global__ __launch_bounds__(256) void k_vt3(
    const unsigned short* __restrict__ qh, const unsigned short* __restrict__ ql,
    unsigned short* __restrict__ vTh, unsigned short* __restrict__ vTl,
    unsigned short* __restrict__ kdTh, unsigned short* __restrict__ kdTl,
    unsigned short* __restrict__ vdTh, unsigned short* __restrict__ vdTl){
  __shared__ unsigned short th[32][33], tl[32][33];
  int z = blockIdx.z, b = z>>4, h = z&15;
  int slice = blockIdx.y >> 1;
  long coff = (slice==0) ? 2048 : (slice==1 ? 4096 : 5120);
  unsigned short* dh = (slice==0) ? vTh : (slice==1 ? kdTh : vdTh);
  unsigned short* dl = (slice==0) ? vTl : (slice==1 ? kdTl : vdTl);
  int s0 = blockIdx.x*32, d0 = (blockIdx.y&1)*32;
  int tx = threadIdx.x & 31, ty = threadIdx.x >> 5;
  for(int i=0;i<32;i+=8){
    long src = (long)(b*SEQ + s0+ty+i)*6144 + coff + h*DK + d0+tx;
    th[ty+i][tx] = qh[src]; tl[ty+i][tx] = ql[src];
  }
  __syncthreads();
  for(int i=0;i<32;i+=8){
    long dst = ((long)z*DK + d0+ty+i)*SEQ + s0+tx;
    dh[dst] = th[tx][ty+i]; dl[dst] = tl[tx][ty+i];
  }
}

// ---- LayerNorm 1: fp32 x -> split bf16 h1 ----------------------------------
__global__ __launch_bounds__(256) void k_ln1(
    const float* __restrict__ x, const float* __restrict__ g,
    const float* __restrict__ b, unsigned short* __restrict__ oh,
    unsigned short* __restrict__ ol){
  __shared__ float red[4];
  int t = blockIdx.x, tid = threadIdx.x;
  long base = (long)t*DMODEL + tid*4;
  floatx4 xv = *(const floatx4*)(x + base);
  float v[4] = {xv[0], xv[1], xv[2], xv[3]};
  float s = block_sum(v[0]+v[1]+v[2]+v[3], red);
  float mu = s * (1.f/DMODEL);
  float q=0.f;
  for(int i=0;i<4;i++){ float d=v[i]-mu; q+=d*d; }
  q = block_sum(q, red);
  float inv = rsqrtf(q*(1.f/DMODEL) + 1e-5f);
  for(int i=0;i<4;i++){
    int d = tid*4+i;
    unsigned short hi,lo; splitbf((v[i]-mu)*inv*g[d] + b[d], hi, lo);
    oh[base+i]=hi; ol[base+i]=lo;
  }
}

// ---- split GEMM, m97 structure + superrow XOR swizzle ----------------------
// R11: per-XCD chunk remapped bx-major with (gridM/8)-deep by minor for L2
// panel reuse. Only call site: qkv (nwg=1536, gridN=48, gridM=32).
template<int SPLIT>
__global__ __launch_bounds__(256) void k_gemm128_ss(
    const unsigned short* __restrict__ Ah, const unsigned short* __restrict__ Al,
    const unsigned short* __restrict__ Bh, const unsigned short* __restrict__ Bl,
    unsigned short* __restrict__ Ch, unsigned short* __restrict__ Cl,
    float* __restrict__ Cf, int K, int lda, int ldb, int ldc, int gridN){
  __shared__ unsigned short Ash[128*32], Asl[128*32];
  __shared__ unsigned short Bsh[128*32], Bsl[128*32];
  int nwg = gridDim.x, bid = blockIdx.x;
  int g = bid & 7, r = bid >> 3;           // XCD-contiguous chunk of nwg/8
  int rpx = (nwg / gridN) >> 3;            // by-rows per XCD (gridM/8)
  int bx = r / rpx, by = g*rpx + (r % rpx);// bx-major, rpx-deep by minor
  int m0 = by*128, n0 = bx*128;
  int tid = threadIdx.x, w = tid>>6, lane = tid&63;
  int qm = lane&15, quad = lane>>4;
  int wr = w>>1, wc = w&1;
  int lg = lane>>3, pp = lane&7, px = pp ^ lg;
  int rowl = (w<<4) + (lg<<1) + (px>>2);             // 0..63 logical row
  int c4s = (px&3)*8;                                 // logical 16B chunk (shorts)
  int sdst = w*512 + lane*8;                          // linear LDS dest
  const unsigned short* pA0h = Ah + (long)(m0+rowl   )*lda + c4s;
  const unsigned short* pA1h = Ah + (long)(m0+rowl+64)*lda + c4s;
  const unsigned short* pA0l = Al + (long)(m0+rowl   )*lda + c4s;
  const unsigned short* pA1l = Al + (long)(m0+rowl+64)*lda + c4s;
  const unsigned short* pB0h = Bh + (long)(n0+rowl   )*ldb + c4s;
  const unsigned short* pB1h = Bh + (long)(n0+rowl+64)*ldb + c4s;
  const unsigned short* pB0l = Bl + (long)(n0+rowl   )*ldb + c4s;
  const unsigned short* pB1l = Bl + (long)(n0+rowl+64)*ldb + c4s;
  int fc = (((((qm&1)<<2)|quad) ^ (qm>>1))<<3);

  floatx4 acc[4][4];
  #pragma unroll
  for(int m=0;m<4;m++)
    #pragma unroll
    for(int n=0;n<4;n++) acc[m][n] = (floatx4){0.f,0.f,0.f,0.f};

  for(int k0=0;k0<K;k0+=32){
    __syncthreads();
    glds16(pA0h+k0, Ash+sdst); glds16(pA1h+k0, Ash+sdst+2048);
    glds16(pA0l+k0, Asl+sdst); glds16(pA1l+k0, Asl+sdst+2048);
    glds16(pB0h+k0, Bsh+sdst); glds16(pB1h+k0, Bsh+sdst+2048);
    glds16(pB0l+k0, Bsl+sdst); glds16(pB1l+k0, Bsl+sdst+2048);
    __syncthreads();
    short8 ah[4], al[4], bh[4], bl[4];
    #pragma unroll
    for(int m=0;m<4;m++){
      int ar = (wr*32 + m*8 + (qm>>1))*64 + fc;
      ah[m] = *(const short8*)(Ash+ar);
      al[m] = *(const short8*)(Asl+ar);
    }
    #pragma unroll
    for(int n=0;n<4;n++){
      int br = (wc*32 + n*8 + (qm>>1))*64 + fc;
      bh[n] = *(const short8*)(Bsh+br);
      bl[n] = *(const short8*)(Bsl+br);
    }
    #pragma unroll
    for(int m=0;m<4;m++)
      #pragma unroll
      for(int n=0;n<4;n++){
        acc[m][n] = __builtin_amdgcn_mfma_f32_16x16x32_bf16(ah[m],bh[n],acc[m][n],0,0,0);
        acc[m][n] = __builtin_amdgcn_mfma_f32_16x16x32_bf16(ah[m],bl[n],acc[m][n],0,0,0);
        acc[m][n] = __builtin_amdgcn_mfma_f32_16x16x32_bf16(al[m],bh[n],acc[m][n],0,0,0);
      }
  }
  #pragma unroll
  for(int m=0;m<4;m++){
    int row = m0 + wr*64 + m*16 + quad*4;
    #pragma unroll
    for(int r2=0;r2<4;r2++){
      long rb = (long)(row+r2)*ldc + n0 + wc*64;
      #pragma unroll
      for(int n=0;n<4;n++){
        float v = acc[m][n][r2];
        if(SPLIT){
          unsigned short hi,lo; splitbf(v,hi,lo);
          Ch[rb+n*16+qm]=hi; Cl[rb+n*16+qm]=lo;
        }else{
          Cf[rb+n*16+qm]=v;
        }
      }
    }
  }
}

// ---- merged output projections, BK=64: dm@WoT -> dproj, dl@WodT -> dlproj --
// 512 blocks = 2/CU; 64KB LDS still allows 2 blocks/CU => occupancy
// unchanged, barrier pairs halved. Accumulation order identical to BK=32.
__global__ __launch_bounds__(256) void k_proj2(
    const unsigned short* __restrict__ dmh, const unsigned short* __restrict__ dml,
    const unsigned short* __restrict__ dlh, const unsigned short* __restrict__ dll,
    const unsigned short* __restrict__ WoTh, const unsigned short* __restrict__ WoTl,
    const unsigned short* __restrict__ WodTh, const unsigned short* __restrict__ WodTl,
    float* __restrict__ dproj, float* __restrict__ dlproj){
  __shared__ unsigned short Ash[128*64], Asl[128*64];
  __shared__ unsigned short Bsh[128*64], Bsl[128*64];
  int bid = blockIdx.x;
  int swz = (bid & 7)*64 + (bid >> 3);               // nwg=512 bijective
  int which = swz >> 8, rem = swz & 255;
  int bx = rem & 7, by = rem >> 3;
  int m0 = by*128, n0 = bx*128;
  const unsigned short* Ah = which ? dlh : dmh;
  const unsigned short* Al = which ? dll : dml;
  const unsigned short* Bh = which ? WodTh : WoTh;
  const unsigned short* Bl = which ? WodTl : WoTl;
  float* Cf = which ? dlproj : dproj;
  int tid = threadIdx.x, w = tid>>6, lane = tid&63;
  int qm = lane&15, quad = lane>>4;
  int wr = w>>1, wc = w&1;
  int lg = lane>>3, pp = lane&7, px = pp ^ lg;
  int rowl = (w<<4) + (lg<<1) + (px>>2);
  int c4s = (px&3)*8;
  int sdst = w*512 + lane*8;
  const unsigned short* pA0h = Ah + (long)(m0+rowl   )*1024 + c4s;
  const unsigned short* pA1h = Ah + (long)(m0+rowl+64)*1024 + c4s;
  const unsigned short* pA0l = Al + (long)(m0+rowl   )*1024 + c4s;
  const unsigned short* pA1l = Al + (long)(m0+rowl+64)*1024 + c4s;
  const unsigned short* pB0h = Bh + (long)(n0+rowl   )*1024 + c4s;
  const unsigned short* pB1h = Bh + (long)(n0+rowl+64)*1024 + c4s;
  const unsigned short* pB0l = Bl + (long)(n0+rowl   )*1024 + c4s;
  const unsigned short* pB1l = Bl + (long)(n0+rowl+64)*1024 + c4s;
  int fc = (((((qm&1)<<2)|quad) ^ (qm>>1))<<3);

  floatx4 acc[4][4];
  #pragma unroll
  for(int m=0;m<4;m++)
    #pragma unroll
    for(int n=0;n<4;n++) acc[m][n] = (floatx4){0.f,0.f,0.f,0.f};

  for(int k0=0;k0<1024;k0+=64){
    __syncthreads();
    // chunk 0 (k0) at LDS offset 0; chunk 1 (k0+32) at offset 4096 shorts
    glds16(pA0h+k0,    Ash+sdst);      glds16(pA1h+k0,    Ash+sdst+2048);
    glds16(pA0h+k0+32, Ash+4096+sdst); glds16(pA1h+k0+32, Ash+4096+sdst+2048);
    glds16(pA0l+k0,    Asl+sdst);      glds16(pA1l+k0,    Asl+sdst+2048);
    glds16(pA0l+k0+32, Asl+4096+sdst); glds16(pA1l+k0+32, Asl+4096+sdst+2048);
    glds16(pB0h+k0,    Bsh+sdst);      glds16(pB1h+k0,    Bsh+sdst+2048);
    glds16(pB0h+k0+32, Bsh+4096+sdst); glds16(pB1h+k0+32, Bsh+4096+sdst+2048);
    glds16(pB0l+k0,    Bsl+sdst);      glds16(pB1l+k0,    Bsl+sdst+2048);
    glds16(pB0l+k0+32, Bsl+4096+sdst); glds16(pB1l+k0+32, Bsl+4096+sdst+2048);
    __syncthreads();
    #pragma unroll
    for(int c=0;c<2;c++){
      int cb = c*4096;
      short8 ah[4], al[4], bh[4], bl[4];
      #pragma unroll
      for(int m=0;m<4;m++){
        int ar = cb + (wr*32 + m*8 + (qm>>1))*64 + fc;
        ah[m] = *(const short8*)(Ash+ar);
        al[m] = *(const short8*)(Asl+ar);
      }
      #pragma unroll
      for(int n=0;n<4;n++){
        int br = cb + (wc*32 + n*8 + (qm>>1))*64 + fc;
        bh[n] = *(const short8*)(Bsh+br);
        bl[n] = *(const short8*)(Bsl+br);
      }
      #pragma unroll
      for(int m=0;m<4;m++)
        #pragma unroll
        for(int n=0;n<4;n++){
          acc[m][n] = __builtin_amdgcn_mfma_f32_16x16x32_bf16(ah[m],bh[n],acc[m][n],0,0,0);
          acc[m][n] = __builtin_amdgcn_mfma_f32_16x16x32_bf16(ah[m],bl[n],acc[m][n],0,0,0);
          acc[m][n] = __builtin_amdgcn_mfma_f32_16x16x32_bf16(al[m],bh[n],acc[m][n],0,0,0);
        }
    }
  }
  #pragma unroll
  for(int m=0;m<4;m++){
    int row = m0 + wr*64 + m*16 + quad*4;
    #pragma unroll
    for(int r=0;r<4;r++){
      long rb = (long)(row+r)*1024 + n0 + wc*64;
      #pragma unroll
      for(int n=0;n<4;n++)
        Cf[rb+n*16+qm] = acc[m][n][r];
    }
  }
}

// ---- gate: softmax(h1 @ w_gate) (h1 split, wg fp32) ------------------------
__global__ __launch_bounds__(256) void k_gate(
    const unsigned short* __restrict__ hh, const unsigned short* __restrict__ hl,
    const float* __restrict__ wg, float* __restrict__ gates){
  int token = blockIdx.x*4 + (threadIdx.x>>6);
  int lane = threadIdx.x&63;
  long hb = (long)token*DMODEL + lane*16;
  const float* w = wg + lane*16*2;
  float s0=0.f, s1=0.f;
  for(int i=0;i<16;i++){
    float hv = bf2f(hh[hb+i]) + bf2f(hl[hb+i]);
    s0 += hv*w[2*i]; s1 += hv*w[2*i+1];
  }
  for(int off=32;off;off>>=1){ s0+=__shfl_down(s0,off,64); s1+=__shfl_down(s1,off,64); }
  if(lane==0){
    float m=fmaxf(s0,s1), e0=__expf(s0-m), e1=__expf(s1-m), inv=1.f/(e0+e1);
    gates[token*2]=e0*inv; gates[token*2+1]=e1*inv;
  }
}

// ---- flash attention v3: K/V staged in LDS (XOR-swizzled), shared by waves -
__global__ __launch_bounds__(256) void k_attn_flash3(
    const unsigned short* __restrict__ qh, const unsigned short* __restrict__ qlp,
    const unsigned short* __restrict__ vth, const unsigned short* __restrict__ vtl,
    const unsigned long long* __restrict__ mp, unsigned short* __restrict__ dmh,
    unsigned short* __restrict__ dml){
  __shared__ unsigned short Ksh[64*64], Ksl[64*64];     // 16KB
  __shared__ unsigned short Vsh[64*64], Vsl[64*64];     // 16KB
  __shared__ unsigned short PWh[4*16*64], PWl[4*16*64]; // 16KB (swizzled)
  int bh = blockIdx.y, b = bh>>4, h = bh&15;
  int tid = threadIdx.x, w = tid>>6, lane = tid&63;
  int qm = lane&15, quad = (lane>>4)&3;
  int q0 = blockIdx.x*64 + w*16;
  long qrow = (long)(b*SEQ+q0+qm)*6144 + h*DK;
  short8 a_qh0 = *(const short8*)(qh +qrow+quad*8);
  short8 a_qh1 = *(const short8*)(qh +qrow+32+quad*8);
  short8 a_ql0 = *(const short8*)(qlp+qrow+quad*8);
  short8 a_ql1 = *(const short8*)(qlp+qrow+32+quad*8);
  float m[4], l[4];
  floatx4 o0={0,0,0,0}, o1={0,0,0,0}, o2={0,0,0,0}, o3={0,0,0,0};
  #pragma unroll
  for(int r=0;r<4;r++){ m[r]=-3.0e38f; l[r]=0.f; }
  const unsigned long long* mrow = mp + ((long)b*SEQ + q0 + quad*4)*16;

  int r8 = lane>>3;                 // row within 8-row stripe
  int c8 = (lane&7) ^ r8;           // inverse-swizzled global chunk
  int d0 = w*512 + lane*8;          // LDS dest (shorts), linear per lane
  const unsigned short* pKh0 = qh  + (long)(b*SEQ + w*8 + r8)*6144 + 1024 + h*DK + c8*8;
  const unsigned short* pKl0 = qlp + (long)(b*SEQ + w*8 + r8)*6144 + 1024 + h*DK + c8*8;
  const unsigned short* pKh1 = pKh0 + 32L*6144;
  const unsigned short* pKl1 = pKl0 + 32L*6144;
  const unsigned short* pVh0 = vth + ((long)bh*DK + w*8 + r8)*SEQ + c8*8;
  const unsigned short* pVl0 = vtl + ((long)bh*DK + w*8 + r8)*SEQ + c8*8;
  const unsigned short* pVh1 = pVh0 + 32L*SEQ;
  const unsigned short* pVl1 = pVl0 + 32L*SEQ;
  int q7 = qm&7;

  for(int kt=0; kt<SEQ; kt+=64){
    __syncthreads();
    long ko = (long)kt*6144;
    glds16(pKh0+ko, Ksh+d0); glds16(pKh1+ko, Ksh+d0+2048);
    glds16(pKl0+ko, Ksl+d0); glds16(pKl1+ko, Ksl+d0+2048);
    glds16(pVh0+kt, Vsh+d0); glds16(pVh1+kt, Vsh+d0+2048);
    glds16(pVl0+kt, Vsl+d0); glds16(pVl1+kt, Vsl+d0+2048);
    __syncthreads();

    int wd = kt>>6;
    unsigned long long mws[4] = {mrow[wd], mrow[16+wd], mrow[32+wd], mrow[48+wd]};
    floatx4 s[4];
    #pragma unroll
    for(int st=0;st<4;st++){
      int krow = (st*16+qm)*64;
      short8 kh0 = *(const short8*)(Ksh + krow + ((quad    ^q7)<<3));
      short8 kh1 = *(const short8*)(Ksh + krow + (((4|quad)^q7)<<3));
      short8 kl0 = *(const short8*)(Ksl + krow + ((quad    ^q7)<<3));
      short8 kl1 = *(const short8*)(Ksl + krow + (((4|quad)^q7)<<3));
      floatx4 acc = {0,0,0,0};
      acc = __builtin_amdgcn_mfma_f32_16x16x32_bf16(a_qh0,kh0,acc,0,0,0);
      acc = __builtin_amdgcn_mfma_f32_16x16x32_bf16(a_qh1,kh1,acc,0,0,0);
      acc = __builtin_amdgcn_mfma_f32_16x16x32_bf16(a_qh0,kl0,acc,0,0,0);
      acc = __builtin_amdgcn_mfma_f32_16x16x32_bf16(a_qh1,kl1,acc,0,0,0);
      acc = __builtin_amdgcn_mfma_f32_16x16x32_bf16(a_ql0,kh0,acc,0,0,0);
      acc = __builtin_amdgcn_mfma_f32_16x16x32_bf16(a_ql1,kh1,acc,0,0,0);
      s[st] = acc;
    }
    #pragma unroll
    for(int r=0;r<4;r++){
      float v0 = ((mws[r]>>(   qm))&1) ? s[0][r]*0.125f : -1e9f;
      float v1 = ((mws[r]>>(16+qm))&1) ? s[1][r]*0.125f : -1e9f;
      float v2 = ((mws[r]>>(32+qm))&1) ? s[2][r]*0.125f : -1e9f;
      float v3 = ((mws[r]>>(48+qm))&1) ? s[3][r]*0.125f : -1e9f;
      float tm = fmaxf(fmaxf(v0,v1), fmaxf(v2,v3));
      tm = fmaxf(tm, __shfl_xor(tm,1,16));
      tm = fmaxf(tm, __shfl_xor(tm,2,16));
      tm = fmaxf(tm, __shfl_xor(tm,4,16));
      tm = fmaxf(tm, __shfl_xor(tm,8,16));
      float nm = fmaxf(m[r], tm);
      float al = __expf(m[r]-nm);
      m[r] = nm;
      float p0=__expf(v0-nm), p1=__expf(v1-nm), p2=__expf(v2-nm), p3=__expf(v3-nm);
      float rs = p0+p1+p2+p3;
      rs += __shfl_xor(rs,1,16); rs += __shfl_xor(rs,2,16);
      rs += __shfl_xor(rs,4,16); rs += __shfl_xor(rs,8,16);
      l[r] = l[r]*al + rs;
      o0[r]*=al; o1[r]*=al; o2[r]*=al; o3[r]*=al;
      int row = quad*4+r, rsw = row&7;
      int pb = w*1024 + row*64 + (qm&7);
      unsigned short hi,lo;
      splitbf(p0,hi,lo); PWh[pb + ((( (qm>>3))^rsw)<<3)]=hi; PWl[pb + ((( (qm>>3))^rsw)<<3)]=lo;
      splitbf(p1,hi,lo); PWh[pb + (((2|(qm>>3))^rsw)<<3)]=hi; PWl[pb + (((2|(qm>>3))^rsw)<<3)]=lo;
      splitbf(p2,hi,lo); PWh[pb + (((4|(qm>>3))^rsw)<<3)]=hi; PWl[pb + (((4|(qm>>3))^rsw)<<3)]=lo;
      splitbf(p3,hi,lo); PWh[pb + (((6|(qm>>3))^rsw)<<3)]=hi; PWl[pb + (((6|(qm>>3))^rsw)<<3)]=lo;
    }
    __builtin_amdgcn_wave_barrier();
    int prb = w*1024 + qm*64;
    short8 ph0 = *(const short8*)(PWh + prb + ((quad    ^q7)<<3));
    short8 ph1 = *(const short8*)(PWh + prb + (((4|quad)^q7)<<3));
    short8 pl0 = *(const short8*)(PWl + prb + ((quad    ^q7)<<3));
    short8 pl1 = *(const short8*)(PWl + prb + (((4|quad)^q7)<<3));
    __builtin_amdgcn_wave_barrier();
    {
      int c0 = (quad    ^q7)<<3;
      int c1 = ((4|quad)^q7)<<3;
      int vr0 = (0*16+qm)*64, vr1 = (1*16+qm)*64, vr2 = (2*16+qm)*64, vr3 = (3*16+qm)*64;
      short8 v0h0=*(const short8*)(Vsh+vr0+c0), v0h1=*(const short8*)(Vsh+vr0+c1);
      short8 v1h0=*(const short8*)(Vsh+vr1+c0), v1h1=*(const short8*)(Vsh+vr1+c1);
      short8 v2h0=*(const short8*)(Vsh+vr2+c0), v2h1=*(const short8*)(Vsh+vr2+c1);
      short8 v3h0=*(const short8*)(Vsh+vr3+c0), v3h1=*(const short8*)(Vsh+vr3+c1);
      short8 v0l0=*(const short8*)(Vsl+vr0+c0), v0l1=*(const short8*)(Vsl+vr0+c1);
      short8 v1l0=*(const short8*)(Vsl+vr1+c0), v1l1=*(const short8*)(Vsl+vr1+c1);
      short8 v2l0=*(const short8*)(Vsl+vr2+c0), v2l1=*(const short8*)(Vsl+vr2+c1);
      short8 v3l0=*(const short8*)(Vsl+vr3+c0), v3l1=*(const short8*)(Vsl+vr3+c1);
      o0 = __builtin_amdgcn_mfma_f32_16x16x32_bf16(ph0,v0h0,o0,0,0,0);
      o0 = __builtin_amdgcn_mfma_f32_16x16x32_bf16(ph1,v0h1,o0,0,0,0);
      o0 = __builtin_amdgcn_mfma_f32_16x16x32_bf16(ph0,v0l0,o0,0,0,0);
      o0 = __builtin_amdgcn_mfma_f32_16x16x32_bf16(ph1,v0l1,o0,0,0,0);
      o0 = __builtin_amdgcn_mfma_f32_16x16x32_bf16(pl0,v0h0,o0,0,0,0);
      o0 = __builtin_amdgcn_mfma_f32_16x16x32_bf16(pl1,v0h1,o0,0,0,0);
      o1 = __builtin_amdgcn_mfma_f32_16x16x32_bf16(ph0,v1h0,o1,0,0,0);
      o1 = __builtin_amdgcn_mfma_f32_16x16x32_bf16(ph1,v1h1,o1,0,0,0);
      o1 = __builtin_amdgcn_mfma_f32_16x16x32_bf16(ph0,v1l0,o1,0,0,0);
      o1 = __builtin_amdgcn_mfma_f32_16x16x32_bf16(ph1,v1l1,o1,0,0,0);
      o1 = __builtin_amdgcn_mfma_f32_16x16x32_bf16(pl0,v1h0,o1,0,0,0);
      o1 = __builtin_amdgcn_mfma_f32_16x16x32_bf16(pl1,v1h1,o1,0,0,0);
      o2 = __builtin_amdgcn_mfma_f32_16x16x32_bf16(ph0,v2h0,o2,0,0,0);
      o2 = __builtin_amdgcn_mfma_f32_16x16x32_bf16(ph1,v2h1,o2,0,0,0);
      o2 = __builtin_amdgcn_mfma_f32_16x16x32_bf16(ph0,v2l0,o2,0,0,0);
      o2 = __builtin_amdgcn_mfma_f32_16x16x32_bf16(ph1,v2l1,o2,0,0,0);
      o2 = __builtin_amdgcn_mfma_f32_16x16x32_bf16(pl0,v2h0,o2,0,0,0);
      o2 = __builtin_amdgcn_mfma_f32_16x16x32_bf16(pl1,v2h1,o2,0,0,0);
      o3 = __builtin_amdgcn_mfma_f32_16x16x32_bf16(ph0,v3h0,o3,0,0,0);
      o3 = __builtin_amdgcn_mfma_f32_16x16x32_bf16(ph1,v3h1,o3,0,0,0);
      o3 = __builtin_amdgcn_mfma_f32_16x16x32_bf16(ph0,v3l0,o3,0,0,0);
      o3 = __builtin_amdgcn_mfma_f32_16x16x32_bf16(ph1,v3l1,o3,0,0,0);
      o3 = __builtin_amdgcn_mfma_f32_16x16x32_bf16(pl0,v3h0,o3,0,0,0);
      o3 = __builtin_amdgcn_mfma_f32_16x16x32_bf16(pl1,v3h1,o3,0,0,0);
    }
  }
  #pragma unroll
  for(int r=0;r<4;r++){
    float inv = 1.f/l[r];
    long rb = ((long)(b*SEQ + q0 + quad*4 + r))*DMODEL + h*DK;
    unsigned short hi,lo;
    splitbf(o0[r]*inv,hi,lo); dmh[rb+   qm]=hi; dml[rb+   qm]=lo;
    splitbf(o1[r]*inv,hi,lo); dmh[rb+16+qm]=hi; dml[rb+16+qm]=lo;
    splitbf(o2[r]*inv,hi,lo); dmh[rb+32+qm]=hi; dml[rb+32+qm]=lo;
    splitbf(o3[r]*inv,hi,lo); dmh[rb+48+qm]=hi; dml[rb+48+qm]=lo;
  }
}

// ---- delta ctx via MFMA + fused ksum ---------------------------------------
__global__ __launch_bounds__(256) void k_delta_ctx2(
    const unsigned short* __restrict__ kdTh, const unsigned short* __restrict__ kdTl,
    const unsigned short* __restrict__ vdTh, const unsigned short* __restrict__ vdTl,
    float* __restrict__ ctx, float* __restrict__ ksum){
  int bh = blockIdx.x;
  int tid = threadIdx.x, w = tid>>6, lane = tid&63;
  int qm = lane&15, quad = lane>>4;
  long abase = ((long)bh*DK + w*16 + qm)*SEQ + quad*8;
  long bbase = ((long)bh*DK + qm)*SEQ + quad*8;
  floatx4 acc[4];
  #pragma unroll
  for(int n=0;n<4;n++) acc[n] = (floatx4){0.f,0.f,0.f,0.f};
  float ks = 0.f;
  #pragma unroll 2
  for(int s0=0;s0<SEQ;s0+=32){
    short8 ah = *(const short8*)(kdTh + abase + s0);
    short8 al = *(const short8*)(kdTl + abase + s0);
    #pragma unroll
    for(int j=0;j<8;j++)
      ks += fmaxf(bf2f((unsigned short)ah[j]) + bf2f((unsigned short)al[j]), 0.f);
    #pragma unroll
    for(int n=0;n<4;n++){
      short8 bh8 = *(const short8*)(vdTh + bbase + (long)n*16*SEQ + s0);
      short8 bl8 = *(const short8*)(vdTl + bbase + (long)n*16*SEQ + s0);
      acc[n] = __builtin_amdgcn_mfma_f32_16x16x32_bf16(ah,bh8,acc[n],0,0,0);
      acc[n] = __builtin_amdgcn_mfma_f32_16x16x32_bf16(ah,bl8,acc[n],0,0,0);
      acc[n] = __builtin_amdgcn_mfma_f32_16x16x32_bf16(al,bh8,acc[n],0,0,0);
    }
  }
  long cb = (long)bh*DK*DK;
  #pragma unroll
  for(int n=0;n<4;n++)
    #pragma unroll
    for(int r=0;r<4;r++)
      ctx[cb + (long)(w*16 + quad*4 + r)*DK + n*16 + qm] = acc[n][r];
  ks += __shfl_xor(ks,16,64);
  ks += __shfl_xor(ks,32,64);
  if(quad==0) ksum[bh*DK + w*16 + qm] = ks;
}

// ---- delta: out = relu(qd)@ctx / z, split-bf16 output ----------------------
__global__ __launch_bounds__(256) void k_delta_out(
    const unsigned short* __restrict__ qh, const unsigned short* __restrict__ qlp,
    const float* __restrict__ ctx, const float* __restrict__ ksum,
    unsigned short* __restrict__ dlh, unsigned short* __restrict__ dll){
  int tok = blockIdx.x, b = tok>>10;
  int tid = threadIdx.x;
  __shared__ float ql[DMODEL];
  long sb = (long)tok*6144 + 3072;
  for(int c=tid;c<DMODEL;c+=256)
    ql[c] = fmaxf(bf2f(qh[sb+c]) + bf2f(qlp[sb+c]), 0.f);
  __syncthreads();
  int h = tid>>4, dg = (tid&15)*4;
  int bh = b*NHEAD + h;
  const float* C = ctx + (long)bh*DK*DK;
  const float* KS = ksum + bh*DK;
  float a0=0,a1=0,a2=0,a3=0,z=0;
  for(int d=0;d<DK;d++){
    float q = ql[h*DK + d];
    z += q * KS[d];
    const float* cr = C + d*DK + dg;
    a0 += q*cr[0]; a1 += q*cr[1]; a2 += q*cr[2]; a3 += q*cr[3];
  }
  float inv = 1.f/(z + 1e-6f);
  long db = (long)tok*DMODEL + h*DK + dg;
  unsigned short hi,lo;
  splitbf(a0*inv,hi,lo); dlh[db  ]=hi; dll[db  ]=lo;
  splitbf(a1*inv,hi,lo); dlh[db+1]=hi; dll[db+1]=lo;
  splitbf(a2*inv,hi,lo); dlh[db+2]=hi; dll[db+2]=lo;
  splitbf(a3*inv,hi,lo); dlh[db+3]=hi; dll[db+3]=lo;
}

// ---- fused: x1 = x+g0*dp+g1*dlp (fp32); h2=LN2(x1); router top2 ------------
__global__ __launch_bounds__(256) void k_comb_router(
    const float* __restrict__ x, const float* __restrict__ dp,
    const float* __restrict__ dlp, const float* __restrict__ gates,
    const float* __restrict__ g, const float* __restrict__ bb,
    const float* __restrict__ wr, unsigned short* __restrict__ h2b,
    float* __restrict__ topw, int* __restrict__ topi, int* __restrict__ counts){
  __shared__ float red[4];
  __shared__ float ered[4][8];
  int t = blockIdx.x, tid = threadIdx.x;
  float g0 = gates[t*2], g1 = gates[t*2+1];
  long base = (long)t*DMODEL + tid*4;
  floatx4 xv = *(const floatx4*)(x + base);
  float v[4];
  for(int i=0;i<4;i++) v[i] = xv[i] + g0*dp[base+i] + g1*dlp[base+i];
  float s = block_sum(v[0]+v[1]+v[2]+v[3], red);
  float mu = s*(1.f/DMODEL);
  float q=0.f; for(int i=0;i<4;i++){ float d=v[i]-mu; q+=d*d; }
  q = block_sum(q, red);
  float inv = rsqrtf(q*(1.f/DMODEL)+1e-5f);
  float a[8]; for(int e=0;e<8;e++) a[e]=0.f;
  for(int i=0;i<4;i++){
    int d = tid*4+i;
    float hv = (v[i]-mu)*inv*g[d] + bb[d];
    h2b[base+i] = f2bf(hv);
    const float* wrow = wr + (long)d*NEXP;
    for(int e=0;e<8;e++) a[e] += hv*wrow[e];
  }
  for(int off=32;off;off>>=1)
    for(int e=0;e<8;e++) a[e] += __shfl_down(a[e],off,64);
  int w = tid>>6;
  if((tid&63)==0) for(int e=0;e<8;e++) ered[w][e]=a[e];
  __syncthreads();
  if(tid==0){
    float lg[8];
    for(int e=0;e<8;e++) lg[e]=ered[0][e]+ered[1][e]+ered[2][e]+ered[3][e];
    int i0=0; for(int e=1;e<8;e++) if(lg[e]>lg[i0]) i0=e;
    int i1=-1; for(int e=0;e<8;e++){ if(e==i0) continue; if(i1<0||lg[e]>lg[i1]) i1=e; }
    float mm=fmaxf(lg[i0],lg[i1]), e0=__expf(lg[i0]-mm), e1=__expf(lg[i1]-mm), s2=1.f/(e0+e1);
    topw[t*2]=e0*s2; topw[t*2+1]=e1*s2;
    topi[t*2]=i0; topi[t*2+1]=i1;
    atomicAdd(&counts[i0],1); atomicAdd(&counts[i1],1);
  }
}

// ---- expert segment offsets + tile table (128-row tiles) -------------------
__global__ void k_meta(const int* __restrict__ counts, int* offs, int* tE,
                       int* tR0, int* tR1, int* ntp, int* cursor){
  if(threadIdx.x==0){
    int o=0, nt=0;
    for(int e=0;e<NEXP;e++){
      offs[e]=o; cursor[e]=0;
      int n=counts[e];
      for(int t=0;t<(n+127)/128;t++){ tE[nt]=e; tR0[nt]=o+t*128; tR1[nt]=o+n; nt++; }
      o+=n;
    }
    offs[NEXP]=o; ntp[0]=nt;
  }
}

// ---- scatter tokens into expert-sorted slots -------------------------------
__global__ __launch_bounds__(256) void k_scatter(
    const int* __restrict__ topi, const int* __restrict__ offs,
    int* cursor, int* perm, int* slotof){
  int token = blockIdx.x*256 + threadIdx.x;
  for(int k=0;k<2;k++){
    int e = topi[token*2+k];
    int pos = atomicAdd(&cursor[e],1);
    int slot = offs[e]+pos;
    perm[slot]=token; slotof[token*2+k]=slot;
  }
}

// ---- MoE GEMM, 128x128 + superrow swizzle, BK=64 (R11) ---------------------
// 32KB LDS keeps 3 blocks/CU; 32 MFMA per barrier-pair (2x the BK=32 rate).
template<int GELU, int GATHER>
__global__ __launch_bounds__(256) void k_moe128(
    const unsigned short* __restrict__ A, const unsigned short* __restrict__ BtA,
    unsigned short* __restrict__ C, const int* __restrict__ perm,
    const int* __restrict__ ntp, const int* __restrict__ tE,
    const int* __restrict__ tR0, const int* __restrict__ tR1,
    int K, int N){
  int bz = blockIdx.y;
  if(bz >= ntp[0]) return;
  int e = tE[bz], r0t = tR0[bz], r1t = tR1[bz];
  __shared__ unsigned short As[128*64], Bs[128*64];
  int tid = threadIdx.x, w = tid>>6, lane = tid&63;
  int qm = lane&15, quad = lane>>4;
  int wr = w>>1, wc = w&1;
  int n0 = blockIdx.x*128;
  int lg = lane>>3, pp = lane&7, px = pp ^ lg;
  int rowl = (w<<4) + (lg<<1) + (px>>2);
  int c4s = (px&3)*8;
  int sdst = w*512 + lane*8;
  int fc = (((((qm&1)<<2)|quad) ^ (qm>>1))<<3);
  int gr0 = r0t + rowl, gr1 = gr0 + 64;
  int gc0 = gr0 < 8191 ? gr0 : 8191;
  int gc1 = gr1 < 8191 ? gr1 : 8191;
  const unsigned short *pA0, *pA1;
  if(GATHER){
    pA0 = A + (long)perm[gc0]*K + c4s;
    pA1 = A + (long)perm[gc1]*K + c4s;
  }else{
    pA0 = A + (long)gc0*K + c4s;
    pA1 = A + (long)gc1*K + c4s;
  }
  const unsigned short* Bt = BtA + (long)e*N*K;
  const unsigned short* pB0 = Bt + (long)(n0+rowl   )*K + c4s;
  const unsigned short* pB1 = Bt + (long)(n0+rowl+64)*K + c4s;

  floatx4 acc[4][4];
  #pragma unroll
  for(int m=0;m<4;m++)
    #pragma unroll
    for(int n=0;n<4;n++) acc[m][n] = (floatx4){0.f,0.f,0.f,0.f};

  for(int k0=0;k0<K;k0+=64){
    __syncthreads();
    glds16(pA0+k0,    As+sdst);      glds16(pA1+k0,    As+sdst+2048);
    glds16(pA0+k0+32, As+4096+sdst); glds16(pA1+k0+32, As+4096+sdst+2048);
    glds16(pB0+k0,    Bs+sdst);      glds16(pB1+k0,    Bs+sdst+2048);
    glds16(pB0+k0+32, Bs+4096+sdst); glds16(pB1+k0+32, Bs+4096+sdst+2048);
    __syncthreads();
    #pragma unroll
    for(int c=0;c<2;c++){
      int cb = c*4096;
      short8 af[4], bf[4];
      #pragma unroll
      for(int m=0;m<4;m++)
        af[m] = *(const short8*)(As + cb + (wr*32 + m*8 + (qm>>1))*64 + fc);
      #pragma unroll
      for(int n=0;n<4;n++)
        bf[n] = *(const short8*)(Bs + cb + (wc*32 + n*8 + (qm>>1))*64 + fc);
      #pragma unroll
      for(int m=0;m<4;m++)
        #pragma unroll
        for(int n=0;n<4;n++)
          acc[m][n] = __builtin_amdgcn_mfma_f32_16x16x32_bf16(af[m],bf[n],acc[m][n],0,0,0);
    }
  }
  #pragma unroll
  for(int m=0;m<4;m++){
    int row = r0t + wr*64 + m*16 + quad*4;
    #pragma unroll
    for(int r=0;r<4;r++){
      if(row+r < r1t){
        long rb = (long)(row+r)*N + n0 + wc*64;
        #pragma unroll
        for(int n=0;n<4;n++){
          float xx = acc[m][n][r];
          if(GELU) xx = 0.5f*xx*(1.f+erff(xx*0.70710678f));
          C[rb+n*16+qm] = f2bf(xx);
        }
      }
    }
  }
}

// ---- final: out = x + g0*dp + g1*dlp + w0*Y[s0] + w1*Y[s1] (fp32) ----------
__global__ __launch_bounds__(256) void k_final(
    const float* __restrict__ x, const float* __restrict__ dp,
    const float* __restrict__ dlp, const float* __restrict__ gates,
    const unsigned short* __restrict__ Y, const int* __restrict__ slotof,
    const float* __restrict__ topw, float* __restrict__ out){
  int t = blockIdx.x, tid = threadIdx.x;
  int s0 = slotof[t*2], s1 = slotof[t*2+1];
  float w0 = topw[t*2], w1 = topw[t*2+1];
  float g0 = gates[t*2], g1 = gates[t*2+1];
  long base = (long)t*DMODEL + tid*4;
  const unsigned short* y0 = Y + (long)s0*DMODEL + tid*4;
  const unsigned short* y1 = Y + (long)s1*DMODEL + tid*4;
  floatx4 xv = *(const floatx4*)(x + base);
  for(int i=0;i<4;i++)
    out[base+i] = xv[i] + g0*dp[base+i] + g1*dlp[base+i]
                        + w0*bf2f(y0[i]) + w1*bf2f(y1[i]);
}

// ===========================================================================
extern "C" void kernel_launch(void* const* d_in, const int* in_sizes, int n_in,
                              void* d_out, int out_size, void* d_ws, size_t ws_size,
                              hipStream_t stream){
  const float* x    = (const float*)d_in[0];
  const int*   mask = (const int*)d_in[1];
  const float* ln1g = (const float*)d_in[2];
  const float* ln1b = (const float*)d_in[3];
  const float* wq   = (const float*)d_in[4];
  const float* wk   = (const float*)d_in[5];
  const float* wv   = (const float*)d_in[6];
  const float* wo   = (const float*)d_in[7];
  const float* wqd  = (const float*)d_in[8];
  const float* wkd  = (const float*)d_in[9];
  const float* wvd  = (const float*)d_in[10];
  const float* wod  = (const float*)d_in[11];
  const float* wg   = (const float*)d_in[12];
  const float* ln2g = (const float*)d_in[13];
  const float* ln2b = (const float*)d_in[14];
  const float* wr   = (const float*)d_in[15];
  const float* ew1  = (const float*)d_in[16];
  const float* ew2  = (const float*)d_in[17];
  float* out = (float*)d_out;

  char* p = (char*)d_ws;
  auto alloc = [&](size_t b)->char*{ char* r=p; p += (b + 255) & ~(size_t)255; return r; };
  unsigned short* WtAllh = (unsigned short*)alloc(6144L*1024*2);
  unsigned short* WtAlll = (unsigned short*)alloc(6144L*1024*2);
  unsigned short* WoTh   = (unsigned short*)alloc(1024L*1024*2);
  unsigned short* WoTl   = (unsigned short*)alloc(1024L*1024*2);
  unsigned short* WodTh  = (unsigned short*)alloc(1024L*1024*2);
  unsigned short* WodTl  = (unsigned short*)alloc(1024L*1024*2);
  unsigned short* eW1T   = (unsigned short*)alloc(8L*2048*1024*2);
  unsigned short* eW2T   = (unsigned short*)alloc(8L*1024*2048*2);
  unsigned short* h1h    = (unsigned short*)alloc(4096L*1024*2);  // later vTh
  unsigned short* h1l    = (unsigned short*)alloc(4096L*1024*2);  // later vTl
  unsigned short* qkvh   = (unsigned short*)alloc(4096L*6144*2);  // later dproj+dlproj (fp32)
  unsigned short* qkvl   = (unsigned short*)alloc(4096L*6144*2);  // later H
  unsigned short* dmh    = (unsigned short*)alloc(4096L*1024*2);  // first vdTh, then attn out, then Y
  unsigned short* dml    = (unsigned short*)alloc(4096L*1024*2);  // first vdTl
  unsigned short* dlh    = (unsigned short*)alloc(4096L*1024*2);  // first kdTh
  unsigned short* dll    = (unsigned short*)alloc(4096L*1024*2);  // first kdTl
  float* ctx   = (float*)alloc(64L*64*64*4);
  float* ksum  = (float*)alloc(64L*64*4);
  float* gates = (float*)alloc(4096L*2*4);
  unsigned short* h2b = (unsigned short*)alloc(4096L*1024*2);
  float* topw = (float*)alloc(4096L*2*4);
  int* topi   = (int*)alloc(4096L*2*4);
  int* slotof = (int*)alloc(4096L*2*4);
  int* perm   = (int*)alloc(8192L*4);
  int* counts = (int*)alloc(64*4);
  int* cursor = (int*)alloc(64*4);
  int* offs   = (int*)alloc(64*4);
  int* ntp    = (int*)alloc(64*4);
  int* tE     = (int*)alloc(MAXTILE*4);
  int* tR0    = (int*)alloc(MAXTILE*4);
  int* tR1    = (int*)alloc(MAXTILE*4);
  unsigned long long* mpack = (unsigned long long*)alloc(4L*1024*16*8);
  if ((size_t)(p - (char*)d_ws) > ws_size) return;  // ws too small -> absmax==ref max

  unsigned short* vTh = h1h;                    // after h1 consumed (qkv gemm + gate)
  unsigned short* vTl = h1l;
  unsigned short* kdTh = dlh;                   // until delta_out overwrites
  unsigned short* kdTl = dll;
  unsigned short* vdTh = dmh;                   // consumed by ctx2 BEFORE attn writes dmh
  unsigned short* vdTl = dml;
  float* dproj  = (float*)qkvh;                 // after qkv consumed (attn+delta)
  float* dlproj = (float*)(qkvh + 8388608);     // second 16.8MB of qkvh region
  unsigned short* H = qkvl;                     // after qkv consumed
  unsigned short* Y = dmh;                      // spans dmh+dml (16.8MB), after projections read dm

  dim3 tb(256);
  // mask bit-pack (independent)
  k_maskpack<<<16384,tb,0,stream>>>(mask, mpack);
  // weight transposes: attention weights split, MoE weights single bf16
  k_transpose_f2<<<dim3(32,32,1),tb,0,stream>>>(wq,  WtAllh+0L*1048576, WtAlll+0L*1048576, 1024,1024, 0,0);
  k_transpose_f2<<<dim3(32,32,1),tb,0,stream>>>(wk,  WtAllh+1L*1048576, WtAlll+1L*1048576, 1024,1024, 0,0);
  k_transpose_f2<<<dim3(32,32,1),tb,0,stream>>>(wv,  WtAllh+2L*1048576, WtAlll+2L*1048576, 1024,1024, 0,0);
  k_transpose_f2<<<dim3(32,32,1),tb,0,stream>>>(wqd, WtAllh+3L*1048576, WtAlll+3L*1048576, 1024,1024, 0,0);
  k_transpose_f2<<<dim3(32,32,1),tb,0,stream>>>(wkd, WtAllh+4L*1048576, WtAlll+4L*1048576, 1024,1024, 0,0);
  k_transpose_f2<<<dim3(32,32,1),tb,0,stream>>>(wvd, WtAllh+5L*1048576, WtAlll+5L*1048576, 1024,1024, 0,0);
  k_transpose_f2<<<dim3(32,32,1),tb,0,stream>>>(wo,  WoTh,  WoTl,  1024,1024, 0,0);
  k_transpose_f2<<<dim3(32,32,1),tb,0,stream>>>(wod, WodTh, WodTl, 1024,1024, 0,0);
  k_transpose_f<<<dim3(64,32,8),tb,0,stream>>>(ew1, eW1T, 2048,1024, 1024L*2048, 2048L*1024);
  k_transpose_f<<<dim3(32,64,8),tb,0,stream>>>(ew2, eW2T, 1024,2048, 2048L*1024, 1024L*2048);
  // LN1 -> h1 split
  k_ln1<<<4096,tb,0,stream>>>(x, ln1g, ln1b, h1h, h1l);
  // qkv: all 6 projections, split in/out. grid 48x32 tiles of 128 (remapped).
  k_gemm128_ss<1><<<dim3(1536),tb,0,stream>>>(h1h,h1l, WtAllh,WtAlll, qkvh,qkvl,nullptr,
                                              1024, 1024, 1024, 6144, 48);
  // gate (fp32 path)
  k_gate<<<1024,tb,0,stream>>>(h1h, h1l, wg, gates);
  // transposed slices: v (attn), kd, vd (delta; vd aliases dmh/dml) — fused
  k_vt3<<<dim3(32,6,64),tb,0,stream>>>(qkvh, qkvl, vTh, vTl, kdTh, kdTl, vdTh, vdTl);
  // delta ctx (+fused ksum) FIRST (consume vdT before attention overwrites dmh/dml)
  k_delta_ctx2<<<64,tb,0,stream>>>(kdTh, kdTl, vdTh, vdTl, ctx, ksum);
  // flash attention v3 (split precision, LDS-staged K/V) -> dmh/dml
  k_attn_flash3<<<dim3(16,64),tb,0,stream>>>(qkvh, qkvl, vTh, vTl, mpack, dmh, dml);
  // delta out (overwrites kdT buffers dlh/dll)
  k_delta_out<<<4096,tb,0,stream>>>(qkvh, qkvl, ctx, ksum, dlh, dll);
  // merged output projections -> fp32 (512 blocks = 2/CU, BK=64)
  k_proj2<<<dim3(512),tb,0,stream>>>(dmh,dml, dlh,dll, WoTh,WoTl, WodTh,WodTl,
                                     dproj, dlproj);
  // residual + gate-mix + LN2 + router (all fp32)
  hipMemsetAsync(counts, 0, NEXP*sizeof(int), stream);
  k_comb_router<<<4096,tb,0,stream>>>(x, dproj, dlproj, gates, ln2g, ln2b, wr,
                                      h2b, topw, topi, counts);
  k_meta<<<1,64,0,stream>>>(counts, offs, tE, tR0, tR1, ntp, cursor);
  k_scatter<<<16,tb,0,stream>>>(topi, offs, cursor, perm, slotof);
  // expert GEMMs (128x128 tiles, BK=64: 3 blocks/CU + 2x MFMA per barrier)
  k_moe128<1,1><<<dim3(16,72),tb,0,stream>>>(h2b, eW1T, H, perm, ntp, tE, tR0, tR1,
                                             1024, 2048);
  k_moe128<0,0><<<dim3(8,72),tb,0,stream>>>(H, eW2T, Y, perm, ntp, tE, tR0, tR1,
                                            2048, 1024);
  // final residual combine
  k_final<<<4096,tb,0,stream>>>(x, dproj, dlproj, gates, Y, slotof, topw, out);
}